// Round 1
// 757.036 us; speedup vs baseline: 1.6065x; 1.6065x over previous
//
#include <hip/hip_runtime.h>
#include <cstdint>

// FP32 external interface (reference is jnp.float32). Intermediates bf16 (u16),
// all accumulation fp32. R6: conv1/conv2 rewritten as MFMA gather-GEMMs.
// Gathered 64-B bf16 records ARE the 16x16x32 B-fragment: lane l loads 16 B at
// record(l&15) + (l>>4)*16. Weights pre-arranged in LDS as A-fragments
// (28 KB conv1 / 14 KB conv2, vs 56 KB f32 before -> occupancy up).

typedef unsigned short u16;
typedef u16 u16x8 __attribute__((ext_vector_type(8)));
typedef float f4 __attribute__((ext_vector_type(4)));
using s16x8 = __attribute__((ext_vector_type(8))) short;
using u16x4 = __attribute__((ext_vector_type(4))) u16;

#define EPS 1e-5f
#define BB 2
#define CIN 64
#define CH 32
#define SVOX 64000
#define NC 100000
#define NF 400000

static __device__ __forceinline__ float b2f(u16 h) {
    return __builtin_bit_cast(float, (unsigned)h << 16);
}
static __device__ __forceinline__ u16 f2b(float f) {
    unsigned u = __builtin_bit_cast(unsigned, f);
    u += 0x7FFFu + ((u >> 16) & 1u);
    return (u16)(u >> 16);
}
static __device__ __forceinline__ f4 mfma16(s16x8 a, s16x8 b, f4 c) {
    return __builtin_amdgcn_mfma_f32_16x16x32_bf16(a, b, c, 0, 0, 0);
}

// ---------------- zero stats accumulators ----------------
__global__ __launch_bounds__(256) void k_zero(float* __restrict__ p, int n) {
    int i = blockIdx.x * 256 + threadIdx.x;
    if (i < n) p[i] = 0.f;
}

// ---------------- transpose x2 f32 [B][32][Nf] -> x2t bf16 [B][Nf][32] ----------
__global__ __launch_bounds__(256) void k_x2t(
    const float* __restrict__ x2, u16* __restrict__ x2t)
{
    __shared__ u16 tile[64][40];
    int tid = threadIdx.x, b = blockIdx.y;
    int n0 = blockIdx.x * 64;
    int c = tid >> 3, no = (tid & 7) * 8;
    const float* src = x2 + ((size_t)b * CH + c) * NF + n0 + no;
    f4 v0 = *(const f4*)src;
    f4 v1 = *(const f4*)(src + 4);
#pragma unroll
    for (int i = 0; i < 4; i++) tile[no + i][c] = f2b(v0[i]);
#pragma unroll
    for (int i = 0; i < 4; i++) tile[no + 4 + i][c] = f2b(v1[i]);
    __syncthreads();
    int n = tid >> 2, co = (tid & 3) * 8;
    u16x8 ov;
#pragma unroll
    for (int i = 0; i < 8; i++) ov[i] = tile[n][co + i];
    *(u16x8*)(x2t + ((size_t)b * NF + n0 + n) * CH + co) = ov;
}

// ---------------- stage A: dense 1x1x1 conv (64 -> 32), y bf16 voxel-major ------
__global__ __launch_bounds__(256) void k_reduce(
    const float* __restrict__ x1, const float* __restrict__ wr,
    u16* __restrict__ y)
{
    __shared__ float wl[CIN * CH];
    int tid = threadIdx.x, b = blockIdx.y;
    for (int i = tid; i < CIN * CH; i += 256) {
        int c = i >> 5, o = i & 31;
        wl[i] = wr[o * CIN + c];   // wl[c][o]
    }
    __syncthreads();
    int s0 = blockIdx.x * 512 + tid;
    int s1 = s0 + 256;
    const float* xb = x1 + (size_t)b * CIN * SVOX;
    float acc0[CH], acc1[CH];
#pragma unroll
    for (int o = 0; o < CH; o++) { acc0[o] = 0.f; acc1[o] = 0.f; }
    for (int c = 0; c < CIN; c++) {
        float xv0 = xb[(size_t)c * SVOX + s0];
        float xv1 = xb[(size_t)c * SVOX + s1];
        const float* w = &wl[c * CH];
#pragma unroll
        for (int o = 0; o < CH; o++) {
            float wv = w[o];
            acc0[o] = fmaf(xv0, wv, acc0[o]);
            acc1[o] = fmaf(xv1, wv, acc1[o]);
        }
    }
    u16* y0 = y + ((size_t)b * SVOX + s0) * CH;
    u16* y1 = y + ((size_t)b * SVOX + s1) * CH;
#pragma unroll
    for (int g = 0; g < 4; g++) {
        u16x8 v0, v1;
#pragma unroll
        for (int i = 0; i < 8; i++) {
            v0[i] = f2b(acc0[g * 8 + i]);
            v1[i] = f2b(acc1[g * 8 + i]);
        }
        ((u16x8*)y0)[g] = v0;
        ((u16x8*)y1)[g] = v1;
    }
}

// ---------------- per-channel stats over rows, bf16 input [B][rows][32] ----------
__global__ __launch_bounds__(256) void k_statsB(
    const u16* __restrict__ x, float* __restrict__ stats, int rows)
{
    __shared__ float sred[CH * 2];
    int tid = threadIdx.x, b = blockIdx.y;
    if (tid < CH * 2) sred[tid] = 0.f;
    __syncthreads();
    int o = tid & 31, stripe = tid >> 5;
    const u16* xb = x + (size_t)b * rows * CH;
    int r0 = blockIdx.x * 512 + stripe * 64;
    float s = 0.f, q = 0.f;
    for (int i = 0; i < 64; i++) {
        int r = r0 + i;
        if (r < rows) {
            float v = b2f(xb[(size_t)r * CH + o]);
            s += v; q = fmaf(v, v, q);
        }
    }
    atomicAdd(&sred[o * 2], s);
    atomicAdd(&sred[o * 2 + 1], q);
    __syncthreads();
    if (tid < CH * 2) atomicAdd(&stats[(size_t)(b * CH * 2 + tid) * 32], sred[tid]);
}

// ---------------- finalize stats -> per-channel scale/shift ----------------
__global__ void k_fin(const float* __restrict__ stats, const float* __restrict__ gamma,
                      const float* __restrict__ beta, float* __restrict__ ss, float invN)
{
    int i = threadIdx.x;
    if (i >= BB * CH) return;
    float sum = stats[(size_t)(i * 2) * 32];
    float sq  = stats[(size_t)(i * 2 + 1) * 32];
    float mean = sum * invN;
    float var = sq * invN - mean * mean;
    float rstd = rsqrtf(var + EPS);
    int o = i & 31;
    float sc = rstd * gamma[o];
    ss[i * 2] = sc;
    ss[i * 2 + 1] = beta[o] - mean * sc;
}

// ---------------- normalized coarse table [B][Nc][32] bf16 ----------------
__global__ __launch_bounds__(256) void k_coarse(
    const u16* __restrict__ y, const float* __restrict__ ssA,
    const int* __restrict__ sidx, u16* __restrict__ coarseN)
{
    __shared__ float sl[CH * 2];
    int tid = threadIdx.x, b = blockIdx.y;
    if (tid < CH * 2) sl[tid] = ssA[b * CH * 2 + tid];
    __syncthreads();
    int u = blockIdx.x * 256 + tid;
    if (u >= NC) return;
    int j = sidx[(size_t)b * NC + u];
    const u16x8* yr = (const u16x8*)(y + ((size_t)b * SVOX + j) * CH);
    u16x8* out = (u16x8*)(coarseN + ((size_t)b * NC + u) * CH);
#pragma unroll
    for (int g = 0; g < 4; g++) {
        u16x8 v = yr[g];
        u16x8 ov;
#pragma unroll
        for (int i = 0; i < 8; i++) {
            int c = g * 8 + i;
            ov[i] = f2b(fmaxf(fmaf(b2f(v[i]), sl[c * 2], sl[c * 2 + 1]), 0.f));
        }
        out[g] = ov;
    }
}

// ---------------- conv1: MFMA gather-GEMM, Cin=64 -> h1 bf16 in d_out ------------
// out[n][o] = sum_{k,c} X[nbr[n][k]][c] * w1[o][c][k]; K = 7k x 2half x 32ch.
// mfma(A=Wfrag 16o x 32k, B=Xfrag 32k x 16p, acc). B-frag comes straight from a
// per-lane dwordx4: record(p = lane&15) + (lane>>4)*16.
__global__ __launch_bounds__(256) void k_conv1(
    const u16* __restrict__ x2t, const u16* __restrict__ coarseN,
    const float* __restrict__ w1, const int* __restrict__ uidx,
    const int* __restrict__ nbr, u16* __restrict__ h1)
{
    __shared__ u16 wf[14 * 2 * 64 * 8];   // 28 KB: [s=k*2+h][ot][lane][j]
    int tid = threadIdx.x, b = blockIdx.y;
    for (int i = tid; i < 14 * 2 * 512; i += 256) {
        int j = i & 7, l = (i >> 3) & 63, ot = (i >> 9) & 1, s = i >> 10;
        int k = s >> 1, h = s & 1;
        int c = h * 32 + (l >> 4) * 8 + j;     // A-frag: k-elem = 8*(lane>>4)+j
        int o = ot * 16 + (l & 15);            // A-frag: row = lane&15
        wf[i] = f2b(w1[(o * CIN + c) * 7 + k]);
    }
    __syncthreads();
    const s16x8* wfv = (const s16x8*)wf;
    int lane = tid & 63, wave = tid >> 6;
    int p = lane & 15, q = lane >> 4;
    const u16* Xlo = x2t + (size_t)b * NF * CH;
    const u16* Xhi = coarseN + (size_t)b * NC * CH;
    const int* nbb = nbr + (size_t)b * NF * 7;
    const int* ub = uidx + (size_t)b * NF;
    for (int t = 0; t < 4; t++) {
        int n = blockIdx.x * 256 + wave * 64 + t * 16 + p;
        bool act = n < NF;
        size_t nn = act ? (size_t)n : 0;
        int i0[7], c0[7];
#pragma unroll
        for (int k = 0; k < 7; k++) i0[k] = nbb[nn * 7 + k];
#pragma unroll
        for (int k = 0; k < 7; k++) c0[k] = ub[i0[k]];
        f4 acc0 = {0.f, 0.f, 0.f, 0.f};
        f4 acc1 = {0.f, 0.f, 0.f, 0.f};
#pragma unroll
        for (int k = 0; k < 7; k++) {
            s16x8 alo = __builtin_bit_cast(s16x8,
                *(const u16x8*)(Xlo + (size_t)i0[k] * CH + q * 8));
            s16x8 ahi = __builtin_bit_cast(s16x8,
                *(const u16x8*)(Xhi + (size_t)c0[k] * CH + q * 8));
            acc0 = mfma16(wfv[(k * 4 + 0) * 64 + lane], alo, acc0);
            acc1 = mfma16(wfv[(k * 4 + 1) * 64 + lane], alo, acc1);
            acc0 = mfma16(wfv[(k * 4 + 2) * 64 + lane], ahi, acc0);
            acc1 = mfma16(wfv[(k * 4 + 3) * 64 + lane], ahi, acc1);
        }
        if (act) {
            // D: col = lane&15 = particle, row = 4*q + r = output channel
            u16x4 v0, v1;
#pragma unroll
            for (int r = 0; r < 4; r++) { v0[r] = f2b(acc0[r]); v1[r] = f2b(acc1[r]); }
            u16* out = h1 + ((size_t)b * NF + n) * CH + q * 4;
            *(u16x4*)out = v0;
            *(u16x4*)(out + 16) = v1;
        }
    }
}

// ---------------- normalize+relu h1 bf16 in place (on d_out) ----------------
__global__ __launch_bounds__(256) void k_norm1b(
    u16* __restrict__ h, const float* __restrict__ ss)
{
    __shared__ float sl[BB * CH * 2];
    int tid = threadIdx.x;
    if (tid < BB * CH * 2) sl[tid] = ss[tid];
    __syncthreads();
    size_t f = ((size_t)blockIdx.x * 256 + tid) * 8;
    int b = (int)(f / ((size_t)NF * CH));
    int c0 = (int)(f & (CH - 1));
    u16x8 v = *(const u16x8*)(h + f);
    u16x8 ov;
#pragma unroll
    for (int i = 0; i < 8; i++) {
        int c = c0 + i;
        ov[i] = f2b(fmaxf(fmaf(b2f(v[i]), sl[(b * CH + c) * 2], sl[(b * CH + c) * 2 + 1]), 0.f));
    }
    *(u16x8*)(h + f) = ov;
}

// ---------------- conv2: MFMA gather-GEMM, Cin=32, bf16 in -> h2 bf16 ------------
__global__ __launch_bounds__(256) void k_conv2(
    const u16* __restrict__ x, const float* __restrict__ w2,
    const int* __restrict__ nbr, u16* __restrict__ h2)
{
    __shared__ u16 wf[7 * 2 * 64 * 8];   // 14 KB: [k][ot][lane][j]
    int tid = threadIdx.x, b = blockIdx.y;
    for (int i = tid; i < 7 * 2 * 512; i += 256) {
        int j = i & 7, l = (i >> 3) & 63, ot = (i >> 9) & 1, k = i >> 10;
        int c = (l >> 4) * 8 + j;
        int o = ot * 16 + (l & 15);
        wf[i] = f2b(w2[(o * CH + c) * 7 + k]);
    }
    __syncthreads();
    const s16x8* wfv = (const s16x8*)wf;
    int lane = tid & 63, wave = tid >> 6;
    int p = lane & 15, q = lane >> 4;
    const u16* Xb = x + (size_t)b * NF * CH;
    const int* nbb = nbr + (size_t)b * NF * 7;
    for (int t = 0; t < 4; t++) {
        int n = blockIdx.x * 256 + wave * 64 + t * 16 + p;
        bool act = n < NF;
        size_t nn = act ? (size_t)n : 0;
        int i0[7];
#pragma unroll
        for (int k = 0; k < 7; k++) i0[k] = nbb[nn * 7 + k];
        f4 acc0 = {0.f, 0.f, 0.f, 0.f};
        f4 acc1 = {0.f, 0.f, 0.f, 0.f};
#pragma unroll
        for (int k = 0; k < 7; k++) {
            s16x8 a = __builtin_bit_cast(s16x8,
                *(const u16x8*)(Xb + (size_t)i0[k] * CH + q * 8));
            acc0 = mfma16(wfv[(k * 2 + 0) * 64 + lane], a, acc0);
            acc1 = mfma16(wfv[(k * 2 + 1) * 64 + lane], a, acc1);
        }
        if (act) {
            u16x4 v0, v1;
#pragma unroll
            for (int r = 0; r < 4; r++) { v0[r] = f2b(acc0[r]); v1[r] = f2b(acc1[r]); }
            u16* out = h2 + ((size_t)b * NF + n) * CH + q * 4;
            *(u16x4*)out = v0;
            *(u16x4*)(out + 16) = v1;
        }
    }
}

// ---------------- normalize+relu+transpose -> d_out f32 [B][32][Nf] --------------
__global__ __launch_bounds__(256) void k_norm2(
    const u16* __restrict__ h, const float* __restrict__ ss, float* __restrict__ out)
{
    __shared__ float sl[CH * 2];
    __shared__ float tile[CH][72];
    int tid = threadIdx.x, b = blockIdx.y;
    if (tid < CH * 2) sl[tid] = ss[b * CH * 2 + tid];
    __syncthreads();
    int n0 = blockIdx.x * 64;
    int p = tid >> 2, c0 = (tid & 3) * 8;
    u16x8 v = *(const u16x8*)(h + ((size_t)b * NF + n0 + p) * CH + c0);
#pragma unroll
    for (int i = 0; i < 8; i++) {
        int c = c0 + i;
        tile[c][p] = fmaxf(fmaf(b2f(v[i]), sl[c * 2], sl[c * 2 + 1]), 0.f);
    }
    __syncthreads();
    int c = tid >> 3, p0 = (tid & 7) * 8;
    f4 o0, o1;
#pragma unroll
    for (int i = 0; i < 4; i++) { o0[i] = tile[c][p0 + i]; o1[i] = tile[c][p0 + 4 + i]; }
    float* dst = out + ((size_t)b * CH + c) * NF + n0 + p0;
    *(f4*)dst = o0;
    *(f4*)(dst + 4) = o1;
}

extern "C" void kernel_launch(void* const* d_in, const int* in_sizes, int n_in,
                              void* d_out, int out_size, void* d_ws, size_t ws_size,
                              hipStream_t stream)
{
    const float* x1 = (const float*)d_in[0];
    const float* x2 = (const float*)d_in[1];
    const float* wr = (const float*)d_in[2];
    const float* gA = (const float*)d_in[3];
    const float* bA = (const float*)d_in[4];
    const float* w1 = (const float*)d_in[5];
    const float* g1 = (const float*)d_in[6];
    const float* b1 = (const float*)d_in[7];
    const float* w2 = (const float*)d_in[8];
    const float* g2 = (const float*)d_in[9];
    const float* b2 = (const float*)d_in[10];
    const int* sidx = (const int*)d_in[11];
    const int* uidx = (const int*)d_in[12];
    const int* nbr  = (const int*)d_in[13];

    // ws (~72.3 MB): x2t bf16 51.2MB (h2 aliases it after conv1) | y bf16 8.19MB |
    // coarseN bf16 12.8MB | stats tail. h1 bf16 [B][Nf][32] = 51.2MB in d_out.
    char* ws = (char*)d_ws;
    u16* x2t     = (u16*)ws;
    u16* h2      = (u16*)ws;                            // alias: x2t dead after conv1
    u16* y       = (u16*)(ws + 51200000);
    u16* coarseN = (u16*)(ws + 59392000);
    float* statsA = (float*)(ws + 72192000);            // 3 x 16 KB padded accumulators
    float* stats1 = (float*)(ws + 72192000 + 16384);
    float* stats2 = (float*)(ws + 72192000 + 32768);
    float* ssA    = (float*)(ws + 72192000 + 49152);    // 3 x 512 B scale/shift tables
    float* ss1    = (float*)(ws + 72192000 + 49664);
    float* ss2    = (float*)(ws + 72192000 + 50176);
    u16* h1 = (u16*)d_out;                              // d_out lower half as bf16 scratch

    k_zero<<<48, 256, 0, stream>>>(statsA, 12288);
    k_x2t<<<dim3(6250, BB), 256, 0, stream>>>(x2, x2t);
    k_reduce<<<dim3(125, BB), 256, 0, stream>>>(x1, wr, y);
    k_statsB<<<dim3(125, BB), 256, 0, stream>>>(y, statsA, SVOX);
    k_fin<<<1, 64, 0, stream>>>(statsA, gA, bA, ssA, 1.f / SVOX);
    k_coarse<<<dim3(391, BB), 256, 0, stream>>>(y, ssA, sidx, coarseN);
    k_conv1<<<dim3(1563, BB), 256, 0, stream>>>(x2t, coarseN, w1, uidx, nbr, h1);
    k_statsB<<<dim3(782, BB), 256, 0, stream>>>(h1, stats1, NF);
    k_fin<<<1, 64, 0, stream>>>(stats1, g1, b1, ss1, 1.f / NF);
    k_norm1b<<<12500, 256, 0, stream>>>(h1, ss1);
    k_conv2<<<dim3(1563, BB), 256, 0, stream>>>(h1, w2, nbr, h2);
    k_statsB<<<dim3(782, BB), 256, 0, stream>>>(h2, stats2, NF);
    k_fin<<<1, 64, 0, stream>>>(stats2, g2, b2, ss2, 1.f / NF);
    k_norm2<<<dim3(6250, BB), 256, 0, stream>>>(h2, ss2, (float*)d_out);
}

// Round 2
// 715.074 us; speedup vs baseline: 1.7008x; 1.0587x over previous
//
#include <hip/hip_runtime.h>
#include <cstdint>

// FP32 external interface (reference is jnp.float32). Intermediates bf16 (u16),
// all accumulation fp32. R7: conv1/conv2 are MFMA gather-GEMMs, restructured for
// latency hiding: 1 particle-tile (16) per wave, all 14 record-gathers issued
// dependency-free, weight A-fragments pre-built in global mem (k_wprep) so each
// block stages LDS with 7 coalesced dwordx4 copies. Occupancy 10 -> 20 waves/CU.

typedef unsigned short u16;
typedef u16 u16x8 __attribute__((ext_vector_type(8)));
typedef float f4 __attribute__((ext_vector_type(4)));
using s16x8 = __attribute__((ext_vector_type(8))) short;
using u16x4 = __attribute__((ext_vector_type(4))) u16;

#define EPS 1e-5f
#define BB 2
#define CIN 64
#define CH 32
#define SVOX 64000
#define NC 100000
#define NF 400000

static __device__ __forceinline__ float b2f(u16 h) {
    return __builtin_bit_cast(float, (unsigned)h << 16);
}
static __device__ __forceinline__ u16 f2b(float f) {
    unsigned u = __builtin_bit_cast(unsigned, f);
    u += 0x7FFFu + ((u >> 16) & 1u);
    return (u16)(u >> 16);
}
static __device__ __forceinline__ f4 mfma16(s16x8 a, s16x8 b, f4 c) {
    return __builtin_amdgcn_mfma_f32_16x16x32_bf16(a, b, c, 0, 0, 0);
}

// ---------------- zero stats accumulators ----------------
__global__ __launch_bounds__(256) void k_zero(float* __restrict__ p, int n) {
    int i = blockIdx.x * 256 + threadIdx.x;
    if (i < n) p[i] = 0.f;
}

// ---------------- pre-build MFMA A-fragment weight tables (one block) ----------
// wf1[(s*2+ot)*512 + l*8 + j]: s = k*2+h, A-frag row o = ot*16+(l&15),
// k-elem c = h*32 + (l>>4)*8 + j.  wf2 same with single half.
__global__ __launch_bounds__(256) void k_wprep(
    const float* __restrict__ w1, const float* __restrict__ w2,
    u16* __restrict__ wf1, u16* __restrict__ wf2)
{
    int tid = threadIdx.x;
    for (int i = tid; i < 14 * 2 * 512; i += 256) {
        int j = i & 7, l = (i >> 3) & 63, ot = (i >> 9) & 1, s = i >> 10;
        int k = s >> 1, h = s & 1;
        int c = h * 32 + (l >> 4) * 8 + j;
        int o = ot * 16 + (l & 15);
        wf1[i] = f2b(w1[(o * CIN + c) * 7 + k]);
    }
    for (int i = tid; i < 7 * 2 * 512; i += 256) {
        int j = i & 7, l = (i >> 3) & 63, ot = (i >> 9) & 1, k = i >> 10;
        int c = (l >> 4) * 8 + j;
        int o = ot * 16 + (l & 15);
        wf2[i] = f2b(w2[(o * CH + c) * 7 + k]);
    }
}

// ---------------- transpose x2 f32 [B][32][Nf] -> x2t bf16 [B][Nf][32] ----------
__global__ __launch_bounds__(256) void k_x2t(
    const float* __restrict__ x2, u16* __restrict__ x2t)
{
    __shared__ u16 tile[64][40];
    int tid = threadIdx.x, b = blockIdx.y;
    int n0 = blockIdx.x * 64;
    int c = tid >> 3, no = (tid & 7) * 8;
    const float* src = x2 + ((size_t)b * CH + c) * NF + n0 + no;
    f4 v0 = *(const f4*)src;
    f4 v1 = *(const f4*)(src + 4);
#pragma unroll
    for (int i = 0; i < 4; i++) tile[no + i][c] = f2b(v0[i]);
#pragma unroll
    for (int i = 0; i < 4; i++) tile[no + 4 + i][c] = f2b(v1[i]);
    __syncthreads();
    int n = tid >> 2, co = (tid & 3) * 8;
    u16x8 ov;
#pragma unroll
    for (int i = 0; i < 8; i++) ov[i] = tile[n][co + i];
    *(u16x8*)(x2t + ((size_t)b * NF + n0 + n) * CH + co) = ov;
}

// ---------------- stage A: dense 1x1x1 conv (64 -> 32), y bf16 voxel-major ------
__global__ __launch_bounds__(256) void k_reduce(
    const float* __restrict__ x1, const float* __restrict__ wr,
    u16* __restrict__ y)
{
    __shared__ float wl[CIN * CH];
    int tid = threadIdx.x, b = blockIdx.y;
    for (int i = tid; i < CIN * CH; i += 256) {
        int c = i >> 5, o = i & 31;
        wl[i] = wr[o * CIN + c];   // wl[c][o]
    }
    __syncthreads();
    int s0 = blockIdx.x * 512 + tid;
    int s1 = s0 + 256;
    const float* xb = x1 + (size_t)b * CIN * SVOX;
    float acc0[CH], acc1[CH];
#pragma unroll
    for (int o = 0; o < CH; o++) { acc0[o] = 0.f; acc1[o] = 0.f; }
    for (int c = 0; c < CIN; c++) {
        float xv0 = xb[(size_t)c * SVOX + s0];
        float xv1 = xb[(size_t)c * SVOX + s1];
        const float* w = &wl[c * CH];
#pragma unroll
        for (int o = 0; o < CH; o++) {
            float wv = w[o];
            acc0[o] = fmaf(xv0, wv, acc0[o]);
            acc1[o] = fmaf(xv1, wv, acc1[o]);
        }
    }
    u16* y0 = y + ((size_t)b * SVOX + s0) * CH;
    u16* y1 = y + ((size_t)b * SVOX + s1) * CH;
#pragma unroll
    for (int g = 0; g < 4; g++) {
        u16x8 v0, v1;
#pragma unroll
        for (int i = 0; i < 8; i++) {
            v0[i] = f2b(acc0[g * 8 + i]);
            v1[i] = f2b(acc1[g * 8 + i]);
        }
        ((u16x8*)y0)[g] = v0;
        ((u16x8*)y1)[g] = v1;
    }
}

// ---------------- per-channel stats over rows, bf16 input [B][rows][32] ----------
__global__ __launch_bounds__(256) void k_statsB(
    const u16* __restrict__ x, float* __restrict__ stats, int rows)
{
    __shared__ float sred[CH * 2];
    int tid = threadIdx.x, b = blockIdx.y;
    if (tid < CH * 2) sred[tid] = 0.f;
    __syncthreads();
    int o = tid & 31, stripe = tid >> 5;
    const u16* xb = x + (size_t)b * rows * CH;
    int r0 = blockIdx.x * 512 + stripe * 64;
    float s = 0.f, q = 0.f;
    for (int i = 0; i < 64; i++) {
        int r = r0 + i;
        if (r < rows) {
            float v = b2f(xb[(size_t)r * CH + o]);
            s += v; q = fmaf(v, v, q);
        }
    }
    atomicAdd(&sred[o * 2], s);
    atomicAdd(&sred[o * 2 + 1], q);
    __syncthreads();
    if (tid < CH * 2) atomicAdd(&stats[(size_t)(b * CH * 2 + tid) * 32], sred[tid]);
}

// ---------------- finalize stats -> per-channel scale/shift ----------------
__global__ void k_fin(const float* __restrict__ stats, const float* __restrict__ gamma,
                      const float* __restrict__ beta, float* __restrict__ ss, float invN)
{
    int i = threadIdx.x;
    if (i >= BB * CH) return;
    float sum = stats[(size_t)(i * 2) * 32];
    float sq  = stats[(size_t)(i * 2 + 1) * 32];
    float mean = sum * invN;
    float var = sq * invN - mean * mean;
    float rstd = rsqrtf(var + EPS);
    int o = i & 31;
    float sc = rstd * gamma[o];
    ss[i * 2] = sc;
    ss[i * 2 + 1] = beta[o] - mean * sc;
}

// ---------------- normalized coarse table [B][Nc][32] bf16 ----------------
__global__ __launch_bounds__(256) void k_coarse(
    const u16* __restrict__ y, const float* __restrict__ ssA,
    const int* __restrict__ sidx, u16* __restrict__ coarseN)
{
    __shared__ float sl[CH * 2];
    int tid = threadIdx.x, b = blockIdx.y;
    if (tid < CH * 2) sl[tid] = ssA[b * CH * 2 + tid];
    __syncthreads();
    int u = blockIdx.x * 256 + tid;
    if (u >= NC) return;
    int j = sidx[(size_t)b * NC + u];
    const u16x8* yr = (const u16x8*)(y + ((size_t)b * SVOX + j) * CH);
    u16x8* out = (u16x8*)(coarseN + ((size_t)b * NC + u) * CH);
#pragma unroll
    for (int g = 0; g < 4; g++) {
        u16x8 v = yr[g];
        u16x8 ov;
#pragma unroll
        for (int i = 0; i < 8; i++) {
            int c = g * 8 + i;
            ov[i] = f2b(fmaxf(fmaf(b2f(v[i]), sl[c * 2], sl[c * 2 + 1]), 0.f));
        }
        out[g] = ov;
    }
}

// ---------------- conv1: MFMA gather-GEMM, 16 particles/wave, 1 tile/wave -------
// out[n][o] = sum_{k,c} X[nbr[n][k]][c] * w1[o][c][k].
// B-frag straight from per-lane dwordx4: record(p=lane&15) + (lane>>4)*16.
__global__ __launch_bounds__(256) void k_conv1(
    const u16* __restrict__ x2t, const u16* __restrict__ coarseN,
    const u16* __restrict__ wfg, const int* __restrict__ uidx,
    const int* __restrict__ nbr, u16* __restrict__ h1)
{
    __shared__ u16 wf[14 * 2 * 512];   // 28 KB
    int tid = threadIdx.x, b = blockIdx.y;
    const f4* wsrc = (const f4*)wfg;
    f4* wdst = (f4*)wf;
#pragma unroll
    for (int i = 0; i < 7; i++) wdst[i * 256 + tid] = wsrc[i * 256 + tid];
    __syncthreads();
    const s16x8* wfv = (const s16x8*)wf;
    int lane = tid & 63, wave = tid >> 6;
    int p = lane & 15, q = lane >> 4;
    int n = blockIdx.x * 64 + wave * 16 + p;   // grid exact: 6250*64 == NF
    const u16* Xlo = x2t + (size_t)b * NF * CH;
    const u16* Xhi = coarseN + (size_t)b * NC * CH;
    const int* nbb = nbr + ((size_t)b * NF + n) * 7;
    const int* ub = uidx + (size_t)b * NF;
    int i0[7], c0[7];
#pragma unroll
    for (int k = 0; k < 7; k++) i0[k] = nbb[k];
#pragma unroll
    for (int k = 0; k < 7; k++) c0[k] = ub[i0[k]];
    s16x8 rlo[7], rhi[7];
#pragma unroll
    for (int k = 0; k < 7; k++)
        rlo[k] = __builtin_bit_cast(s16x8, *(const u16x8*)(Xlo + (size_t)i0[k] * CH + q * 8));
#pragma unroll
    for (int k = 0; k < 7; k++)
        rhi[k] = __builtin_bit_cast(s16x8, *(const u16x8*)(Xhi + (size_t)c0[k] * CH + q * 8));
    f4 acc0 = {0.f, 0.f, 0.f, 0.f};
    f4 acc1 = {0.f, 0.f, 0.f, 0.f};
#pragma unroll
    for (int k = 0; k < 7; k++) {
        acc0 = mfma16(wfv[(k * 4 + 0) * 64 + lane], rlo[k], acc0);
        acc1 = mfma16(wfv[(k * 4 + 1) * 64 + lane], rlo[k], acc1);
        acc0 = mfma16(wfv[(k * 4 + 2) * 64 + lane], rhi[k], acc0);
        acc1 = mfma16(wfv[(k * 4 + 3) * 64 + lane], rhi[k], acc1);
    }
    // D: col = lane&15 = particle, row = 4*q + r = output channel
    u16x4 v0, v1;
#pragma unroll
    for (int r = 0; r < 4; r++) { v0[r] = f2b(acc0[r]); v1[r] = f2b(acc1[r]); }
    u16* out = h1 + ((size_t)b * NF + n) * CH + q * 4;
    *(u16x4*)out = v0;
    *(u16x4*)(out + 16) = v1;
}

// ---------------- normalize+relu h1 bf16 in place (on d_out) ----------------
__global__ __launch_bounds__(256) void k_norm1b(
    u16* __restrict__ h, const float* __restrict__ ss)
{
    __shared__ float sl[BB * CH * 2];
    int tid = threadIdx.x;
    if (tid < BB * CH * 2) sl[tid] = ss[tid];
    __syncthreads();
    size_t f = ((size_t)blockIdx.x * 256 + tid) * 8;
    int b = (int)(f / ((size_t)NF * CH));
    int c0 = (int)(f & (CH - 1));
    u16x8 v = *(const u16x8*)(h + f);
    u16x8 ov;
#pragma unroll
    for (int i = 0; i < 8; i++) {
        int c = c0 + i;
        ov[i] = f2b(fmaxf(fmaf(b2f(v[i]), sl[(b * CH + c) * 2], sl[(b * CH + c) * 2 + 1]), 0.f));
    }
    *(u16x8*)(h + f) = ov;
}

// ---------------- conv2: MFMA gather-GEMM, Cin=32, 16 particles/wave ------------
__global__ __launch_bounds__(256) void k_conv2(
    const u16* __restrict__ x, const u16* __restrict__ wfg,
    const int* __restrict__ nbr, u16* __restrict__ h2)
{
    __shared__ u16 wf[7 * 2 * 512];   // 14 KB
    int tid = threadIdx.x, b = blockIdx.y;
    const f4* wsrc = (const f4*)wfg;
    f4* wdst = (f4*)wf;
#pragma unroll
    for (int i = 0; i < 3; i++) wdst[i * 256 + tid] = wsrc[i * 256 + tid];
    if (tid < 128) wdst[768 + tid] = wsrc[768 + tid];
    __syncthreads();
    const s16x8* wfv = (const s16x8*)wf;
    int lane = tid & 63, wave = tid >> 6;
    int p = lane & 15, q = lane >> 4;
    int n = blockIdx.x * 64 + wave * 16 + p;
    const u16* Xb = x + (size_t)b * NF * CH;
    const int* nbb = nbr + ((size_t)b * NF + n) * 7;
    int i0[7];
#pragma unroll
    for (int k = 0; k < 7; k++) i0[k] = nbb[k];
    s16x8 r[7];
#pragma unroll
    for (int k = 0; k < 7; k++)
        r[k] = __builtin_bit_cast(s16x8, *(const u16x8*)(Xb + (size_t)i0[k] * CH + q * 8));
    f4 acc0 = {0.f, 0.f, 0.f, 0.f};
    f4 acc1 = {0.f, 0.f, 0.f, 0.f};
#pragma unroll
    for (int k = 0; k < 7; k++) {
        acc0 = mfma16(wfv[(k * 2 + 0) * 64 + lane], r[k], acc0);
        acc1 = mfma16(wfv[(k * 2 + 1) * 64 + lane], r[k], acc1);
    }
    u16x4 v0, v1;
#pragma unroll
    for (int rr = 0; rr < 4; rr++) { v0[rr] = f2b(acc0[rr]); v1[rr] = f2b(acc1[rr]); }
    u16* out = h2 + ((size_t)b * NF + n) * CH + q * 4;
    *(u16x4*)out = v0;
    *(u16x4*)(out + 16) = v1;
}

// ---------------- normalize+relu+transpose -> d_out f32 [B][32][Nf] --------------
__global__ __launch_bounds__(256) void k_norm2(
    const u16* __restrict__ h, const float* __restrict__ ss, float* __restrict__ out)
{
    __shared__ float sl[CH * 2];
    __shared__ float tile[CH][72];
    int tid = threadIdx.x, b = blockIdx.y;
    if (tid < CH * 2) sl[tid] = ss[b * CH * 2 + tid];
    __syncthreads();
    int n0 = blockIdx.x * 64;
    int p = tid >> 2, c0 = (tid & 3) * 8;
    u16x8 v = *(const u16x8*)(h + ((size_t)b * NF + n0 + p) * CH + c0);
#pragma unroll
    for (int i = 0; i < 8; i++) {
        int c = c0 + i;
        tile[c][p] = fmaxf(fmaf(b2f(v[i]), sl[c * 2], sl[c * 2 + 1]), 0.f);
    }
    __syncthreads();
    int c = tid >> 3, p0 = (tid & 7) * 8;
    f4 o0, o1;
#pragma unroll
    for (int i = 0; i < 4; i++) { o0[i] = tile[c][p0 + i]; o1[i] = tile[c][p0 + 4 + i]; }
    float* dst = out + ((size_t)b * CH + c) * NF + n0 + p0;
    *(f4*)dst = o0;
    *(f4*)(dst + 4) = o1;
}

extern "C" void kernel_launch(void* const* d_in, const int* in_sizes, int n_in,
                              void* d_out, int out_size, void* d_ws, size_t ws_size,
                              hipStream_t stream)
{
    const float* x1 = (const float*)d_in[0];
    const float* x2 = (const float*)d_in[1];
    const float* wr = (const float*)d_in[2];
    const float* gA = (const float*)d_in[3];
    const float* bA = (const float*)d_in[4];
    const float* w1 = (const float*)d_in[5];
    const float* g1 = (const float*)d_in[6];
    const float* b1 = (const float*)d_in[7];
    const float* w2 = (const float*)d_in[8];
    const float* g2 = (const float*)d_in[9];
    const float* b2 = (const float*)d_in[10];
    const int* sidx = (const int*)d_in[11];
    const int* uidx = (const int*)d_in[12];
    const int* nbr  = (const int*)d_in[13];

    // ws (~72.3 MB): x2t bf16 51.2MB (h2 aliases it after conv1) | y bf16 8.19MB |
    // coarseN bf16 12.8MB | stats tail. h1 bf16 [B][Nf][32] = 51.2MB in d_out's
    // lower half; weight-fragment tables live in d_out's upper half (dead until
    // k_norm2 overwrites the whole output at the end).
    char* ws = (char*)d_ws;
    u16* x2t     = (u16*)ws;
    u16* h2      = (u16*)ws;                            // alias: x2t dead after conv1
    u16* y       = (u16*)(ws + 51200000);
    u16* coarseN = (u16*)(ws + 59392000);
    float* statsA = (float*)(ws + 72192000);            // 3 x 16 KB padded accumulators
    float* stats1 = (float*)(ws + 72192000 + 16384);
    float* stats2 = (float*)(ws + 72192000 + 32768);
    float* ssA    = (float*)(ws + 72192000 + 49152);    // 3 x 512 B scale/shift tables
    float* ss1    = (float*)(ws + 72192000 + 49664);
    float* ss2    = (float*)(ws + 72192000 + 50176);
    u16* h1  = (u16*)d_out;                             // d_out lower half as bf16 scratch
    u16* wf1g = (u16*)((char*)d_out + 96000000);        // 28672 B, dead before k_norm2
    u16* wf2g = (u16*)((char*)d_out + 96000000 + 28672);// 14336 B

    k_zero<<<48, 256, 0, stream>>>(statsA, 12288);
    k_wprep<<<1, 256, 0, stream>>>(w1, w2, wf1g, wf2g);
    k_x2t<<<dim3(6250, BB), 256, 0, stream>>>(x2, x2t);
    k_reduce<<<dim3(125, BB), 256, 0, stream>>>(x1, wr, y);
    k_statsB<<<dim3(125, BB), 256, 0, stream>>>(y, statsA, SVOX);
    k_fin<<<1, 64, 0, stream>>>(statsA, gA, bA, ssA, 1.f / SVOX);
    k_coarse<<<dim3(391, BB), 256, 0, stream>>>(y, ssA, sidx, coarseN);
    k_conv1<<<dim3(6250, BB), 256, 0, stream>>>(x2t, coarseN, wf1g, uidx, nbr, h1);
    k_statsB<<<dim3(782, BB), 256, 0, stream>>>(h1, stats1, NF);
    k_fin<<<1, 64, 0, stream>>>(stats1, g1, b1, ss1, 1.f / NF);
    k_norm1b<<<12500, 256, 0, stream>>>(h1, ss1);
    k_conv2<<<dim3(6250, BB), 256, 0, stream>>>(h1, wf2g, nbr, h2);
    k_statsB<<<dim3(782, BB), 256, 0, stream>>>(h2, stats2, NF);
    k_fin<<<1, 64, 0, stream>>>(stats2, g2, b2, ss2, 1.f / NF);
    k_norm2<<<dim3(6250, BB), 256, 0, stream>>>(h2, ss2, (float*)d_out);
}

// Round 3
// 698.855 us; speedup vs baseline: 1.7403x; 1.0232x over previous
//
#include <hip/hip_runtime.h>
#include <cstdint>

// FP32 external interface (reference is jnp.float32). Intermediates bf16 (u16),
// all accumulation fp32. R8: conv1/conv2 MFMA gather-GEMMs at 512-thread blocks
// (8 waves share one LDS weight table -> 32 waves/CU occupancy cap, was 20) and
// norm1+relu fused into conv2's gather path (k_norm1b kernel deleted; gathered
// raw h1 records normalized in-register before the MFMA).

typedef unsigned short u16;
typedef u16 u16x8 __attribute__((ext_vector_type(8)));
typedef float f4 __attribute__((ext_vector_type(4)));
using s16x8 = __attribute__((ext_vector_type(8))) short;
using u16x4 = __attribute__((ext_vector_type(4))) u16;

#define EPS 1e-5f
#define BB 2
#define CIN 64
#define CH 32
#define SVOX 64000
#define NC 100000
#define NF 400000

static __device__ __forceinline__ float b2f(u16 h) {
    return __builtin_bit_cast(float, (unsigned)h << 16);
}
static __device__ __forceinline__ u16 f2b(float f) {
    unsigned u = __builtin_bit_cast(unsigned, f);
    u += 0x7FFFu + ((u >> 16) & 1u);
    return (u16)(u >> 16);
}
static __device__ __forceinline__ f4 mfma16(s16x8 a, s16x8 b, f4 c) {
    return __builtin_amdgcn_mfma_f32_16x16x32_bf16(a, b, c, 0, 0, 0);
}

// ---------------- zero stats accumulators ----------------
__global__ __launch_bounds__(256) void k_zero(float* __restrict__ p, int n) {
    int i = blockIdx.x * 256 + threadIdx.x;
    if (i < n) p[i] = 0.f;
}

// ---------------- pre-build MFMA A-fragment weight tables (one block) ----------
__global__ __launch_bounds__(256) void k_wprep(
    const float* __restrict__ w1, const float* __restrict__ w2,
    u16* __restrict__ wf1, u16* __restrict__ wf2)
{
    int tid = threadIdx.x;
    for (int i = tid; i < 14 * 2 * 512; i += 256) {
        int j = i & 7, l = (i >> 3) & 63, ot = (i >> 9) & 1, s = i >> 10;
        int k = s >> 1, h = s & 1;
        int c = h * 32 + (l >> 4) * 8 + j;
        int o = ot * 16 + (l & 15);
        wf1[i] = f2b(w1[(o * CIN + c) * 7 + k]);
    }
    for (int i = tid; i < 7 * 2 * 512; i += 256) {
        int j = i & 7, l = (i >> 3) & 63, ot = (i >> 9) & 1, k = i >> 10;
        int c = (l >> 4) * 8 + j;
        int o = ot * 16 + (l & 15);
        wf2[i] = f2b(w2[(o * CH + c) * 7 + k]);
    }
}

// ---------------- transpose x2 f32 [B][32][Nf] -> x2t bf16 [B][Nf][32] ----------
__global__ __launch_bounds__(256) void k_x2t(
    const float* __restrict__ x2, u16* __restrict__ x2t)
{
    __shared__ u16 tile[64][40];
    int tid = threadIdx.x, b = blockIdx.y;
    int n0 = blockIdx.x * 64;
    int c = tid >> 3, no = (tid & 7) * 8;
    const float* src = x2 + ((size_t)b * CH + c) * NF + n0 + no;
    f4 v0 = *(const f4*)src;
    f4 v1 = *(const f4*)(src + 4);
#pragma unroll
    for (int i = 0; i < 4; i++) tile[no + i][c] = f2b(v0[i]);
#pragma unroll
    for (int i = 0; i < 4; i++) tile[no + 4 + i][c] = f2b(v1[i]);
    __syncthreads();
    int n = tid >> 2, co = (tid & 3) * 8;
    u16x8 ov;
#pragma unroll
    for (int i = 0; i < 8; i++) ov[i] = tile[n][co + i];
    *(u16x8*)(x2t + ((size_t)b * NF + n0 + n) * CH + co) = ov;
}

// ---------------- stage A: dense 1x1x1 conv (64 -> 32), y bf16 voxel-major ------
__global__ __launch_bounds__(256) void k_reduce(
    const float* __restrict__ x1, const float* __restrict__ wr,
    u16* __restrict__ y)
{
    __shared__ float wl[CIN * CH];
    int tid = threadIdx.x, b = blockIdx.y;
    for (int i = tid; i < CIN * CH; i += 256) {
        int c = i >> 5, o = i & 31;
        wl[i] = wr[o * CIN + c];   // wl[c][o]
    }
    __syncthreads();
    int s0 = blockIdx.x * 512 + tid;
    int s1 = s0 + 256;
    const float* xb = x1 + (size_t)b * CIN * SVOX;
    float acc0[CH], acc1[CH];
#pragma unroll
    for (int o = 0; o < CH; o++) { acc0[o] = 0.f; acc1[o] = 0.f; }
    for (int c = 0; c < CIN; c++) {
        float xv0 = xb[(size_t)c * SVOX + s0];
        float xv1 = xb[(size_t)c * SVOX + s1];
        const float* w = &wl[c * CH];
#pragma unroll
        for (int o = 0; o < CH; o++) {
            float wv = w[o];
            acc0[o] = fmaf(xv0, wv, acc0[o]);
            acc1[o] = fmaf(xv1, wv, acc1[o]);
        }
    }
    u16* y0 = y + ((size_t)b * SVOX + s0) * CH;
    u16* y1 = y + ((size_t)b * SVOX + s1) * CH;
#pragma unroll
    for (int g = 0; g < 4; g++) {
        u16x8 v0, v1;
#pragma unroll
        for (int i = 0; i < 8; i++) {
            v0[i] = f2b(acc0[g * 8 + i]);
            v1[i] = f2b(acc1[g * 8 + i]);
        }
        ((u16x8*)y0)[g] = v0;
        ((u16x8*)y1)[g] = v1;
    }
}

// ---------------- per-channel stats over rows, bf16 input [B][rows][32] ----------
__global__ __launch_bounds__(256) void k_statsB(
    const u16* __restrict__ x, float* __restrict__ stats, int rows)
{
    __shared__ float sred[CH * 2];
    int tid = threadIdx.x, b = blockIdx.y;
    if (tid < CH * 2) sred[tid] = 0.f;
    __syncthreads();
    int o = tid & 31, stripe = tid >> 5;
    const u16* xb = x + (size_t)b * rows * CH;
    int r0 = blockIdx.x * 512 + stripe * 64;
    float s = 0.f, q = 0.f;
    for (int i = 0; i < 64; i++) {
        int r = r0 + i;
        if (r < rows) {
            float v = b2f(xb[(size_t)r * CH + o]);
            s += v; q = fmaf(v, v, q);
        }
    }
    atomicAdd(&sred[o * 2], s);
    atomicAdd(&sred[o * 2 + 1], q);
    __syncthreads();
    if (tid < CH * 2) atomicAdd(&stats[(size_t)(b * CH * 2 + tid) * 32], sred[tid]);
}

// ---------------- finalize stats -> per-channel scale/shift ----------------
__global__ void k_fin(const float* __restrict__ stats, const float* __restrict__ gamma,
                      const float* __restrict__ beta, float* __restrict__ ss, float invN)
{
    int i = threadIdx.x;
    if (i >= BB * CH) return;
    float sum = stats[(size_t)(i * 2) * 32];
    float sq  = stats[(size_t)(i * 2 + 1) * 32];
    float mean = sum * invN;
    float var = sq * invN - mean * mean;
    float rstd = rsqrtf(var + EPS);
    int o = i & 31;
    float sc = rstd * gamma[o];
    ss[i * 2] = sc;
    ss[i * 2 + 1] = beta[o] - mean * sc;
}

// ---------------- normalized coarse table [B][Nc][32] bf16 ----------------
__global__ __launch_bounds__(256) void k_coarse(
    const u16* __restrict__ y, const float* __restrict__ ssA,
    const int* __restrict__ sidx, u16* __restrict__ coarseN)
{
    __shared__ float sl[CH * 2];
    int tid = threadIdx.x, b = blockIdx.y;
    if (tid < CH * 2) sl[tid] = ssA[b * CH * 2 + tid];
    __syncthreads();
    int u = blockIdx.x * 256 + tid;
    if (u >= NC) return;
    int j = sidx[(size_t)b * NC + u];
    const u16x8* yr = (const u16x8*)(y + ((size_t)b * SVOX + j) * CH);
    u16x8* out = (u16x8*)(coarseN + ((size_t)b * NC + u) * CH);
#pragma unroll
    for (int g = 0; g < 4; g++) {
        u16x8 v = yr[g];
        u16x8 ov;
#pragma unroll
        for (int i = 0; i < 8; i++) {
            int c = g * 8 + i;
            ov[i] = f2b(fmaxf(fmaf(b2f(v[i]), sl[c * 2], sl[c * 2 + 1]), 0.f));
        }
        out[g] = ov;
    }
}

// ---------------- conv1: MFMA gather-GEMM, 512 thr, 16 particles/wave ----------
// out[n][o] = sum_{k,c} X[nbr[n][k]][c] * w1[o][c][k].
// B-frag straight from per-lane dwordx4: record(p=lane&15) + (lane>>4)*16.
__global__ __launch_bounds__(512) void k_conv1(
    const u16* __restrict__ x2t, const u16* __restrict__ coarseN,
    const u16* __restrict__ wfg, const int* __restrict__ uidx,
    const int* __restrict__ nbr, u16* __restrict__ h1)
{
    __shared__ u16 wf[14 * 2 * 512];   // 28 KB shared by 8 waves
    int tid = threadIdx.x, b = blockIdx.y;
    const f4* wsrc = (const f4*)wfg;
    f4* wdst = (f4*)wf;
    for (int i = tid; i < 1792; i += 512) wdst[i] = wsrc[i];
    __syncthreads();
    const s16x8* wfv = (const s16x8*)wf;
    int lane = tid & 63, wave = tid >> 6;
    int p = lane & 15, q = lane >> 4;
    int n = blockIdx.x * 128 + wave * 16 + p;   // grid exact: 3125*128 == NF
    const u16* Xlo = x2t + (size_t)b * NF * CH;
    const u16* Xhi = coarseN + (size_t)b * NC * CH;
    const int* nbb = nbr + ((size_t)b * NF + n) * 7;
    const int* ub = uidx + (size_t)b * NF;
    int i0[7], c0[7];
#pragma unroll
    for (int k = 0; k < 7; k++) i0[k] = nbb[k];
#pragma unroll
    for (int k = 0; k < 7; k++) c0[k] = ub[i0[k]];
    s16x8 rlo[7], rhi[7];
#pragma unroll
    for (int k = 0; k < 7; k++)
        rlo[k] = __builtin_bit_cast(s16x8, *(const u16x8*)(Xlo + (size_t)i0[k] * CH + q * 8));
#pragma unroll
    for (int k = 0; k < 7; k++)
        rhi[k] = __builtin_bit_cast(s16x8, *(const u16x8*)(Xhi + (size_t)c0[k] * CH + q * 8));
    f4 acc0 = {0.f, 0.f, 0.f, 0.f};
    f4 acc1 = {0.f, 0.f, 0.f, 0.f};
#pragma unroll
    for (int k = 0; k < 7; k++) {
        acc0 = mfma16(wfv[(k * 4 + 0) * 64 + lane], rlo[k], acc0);
        acc1 = mfma16(wfv[(k * 4 + 1) * 64 + lane], rlo[k], acc1);
        acc0 = mfma16(wfv[(k * 4 + 2) * 64 + lane], rhi[k], acc0);
        acc1 = mfma16(wfv[(k * 4 + 3) * 64 + lane], rhi[k], acc1);
    }
    // D: col = lane&15 = particle, row = 4*q + r = output channel
    u16x4 v0, v1;
#pragma unroll
    for (int r = 0; r < 4; r++) { v0[r] = f2b(acc0[r]); v1[r] = f2b(acc1[r]); }
    u16* out = h1 + ((size_t)b * NF + n) * CH + q * 4;
    *(u16x4*)out = v0;
    *(u16x4*)(out + 16) = v1;
}

// ---------------- conv2: MFMA gather-GEMM, 512 thr, norm1+relu fused ------------
// Gathers RAW h1 records and applies y = relu(v*sc+sh) in-register (exactly the
// rounding sequence the old k_norm1b + re-read path produced).
__global__ __launch_bounds__(512) void k_conv2(
    const u16* __restrict__ x, const u16* __restrict__ wfg,
    const int* __restrict__ nbr, const float* __restrict__ ss1,
    u16* __restrict__ h2)
{
    __shared__ u16 wf[7 * 2 * 512];   // 14 KB shared by 8 waves
    int tid = threadIdx.x, b = blockIdx.y;
    const f4* wsrc = (const f4*)wfg;
    f4* wdst = (f4*)wf;
    for (int i = tid; i < 896; i += 512) wdst[i] = wsrc[i];
    __syncthreads();
    const s16x8* wfv = (const s16x8*)wf;
    int lane = tid & 63, wave = tid >> 6;
    int p = lane & 15, q = lane >> 4;
    int n = blockIdx.x * 128 + wave * 16 + p;
    const u16* Xb = x + (size_t)b * NF * CH;
    const int* nbb = nbr + ((size_t)b * NF + n) * 7;
    float sc[8], sh[8];
#pragma unroll
    for (int j = 0; j < 8; j++) {
        sc[j] = ss1[(b * CH + q * 8 + j) * 2];
        sh[j] = ss1[(b * CH + q * 8 + j) * 2 + 1];
    }
    int i0[7];
#pragma unroll
    for (int k = 0; k < 7; k++) i0[k] = nbb[k];
    u16x8 raw[7];
#pragma unroll
    for (int k = 0; k < 7; k++)
        raw[k] = *(const u16x8*)(Xb + (size_t)i0[k] * CH + q * 8);
    f4 acc0 = {0.f, 0.f, 0.f, 0.f};
    f4 acc1 = {0.f, 0.f, 0.f, 0.f};
#pragma unroll
    for (int k = 0; k < 7; k++) {
        u16x8 nv;
#pragma unroll
        for (int j = 0; j < 8; j++)
            nv[j] = f2b(fmaxf(fmaf(b2f(raw[k][j]), sc[j], sh[j]), 0.f));
        s16x8 a = __builtin_bit_cast(s16x8, nv);
        acc0 = mfma16(wfv[(k * 2 + 0) * 64 + lane], a, acc0);
        acc1 = mfma16(wfv[(k * 2 + 1) * 64 + lane], a, acc1);
    }
    u16x4 v0, v1;
#pragma unroll
    for (int rr = 0; rr < 4; rr++) { v0[rr] = f2b(acc0[rr]); v1[rr] = f2b(acc1[rr]); }
    u16* out = h2 + ((size_t)b * NF + n) * CH + q * 4;
    *(u16x4*)out = v0;
    *(u16x4*)(out + 16) = v1;
}

// ---------------- normalize+relu+transpose -> d_out f32 [B][32][Nf] --------------
__global__ __launch_bounds__(256) void k_norm2(
    const u16* __restrict__ h, const float* __restrict__ ss, float* __restrict__ out)
{
    __shared__ float sl[CH * 2];
    __shared__ float tile[CH][72];
    int tid = threadIdx.x, b = blockIdx.y;
    if (tid < CH * 2) sl[tid] = ss[b * CH * 2 + tid];
    __syncthreads();
    int n0 = blockIdx.x * 64;
    int p = tid >> 2, c0 = (tid & 3) * 8;
    u16x8 v = *(const u16x8*)(h + ((size_t)b * NF + n0 + p) * CH + c0);
#pragma unroll
    for (int i = 0; i < 8; i++) {
        int c = c0 + i;
        tile[c][p] = fmaxf(fmaf(b2f(v[i]), sl[c * 2], sl[c * 2 + 1]), 0.f);
    }
    __syncthreads();
    int c = tid >> 3, p0 = (tid & 7) * 8;
    f4 o0, o1;
#pragma unroll
    for (int i = 0; i < 4; i++) { o0[i] = tile[c][p0 + i]; o1[i] = tile[c][p0 + 4 + i]; }
    float* dst = out + ((size_t)b * CH + c) * NF + n0 + p0;
    *(f4*)dst = o0;
    *(f4*)(dst + 4) = o1;
}

extern "C" void kernel_launch(void* const* d_in, const int* in_sizes, int n_in,
                              void* d_out, int out_size, void* d_ws, size_t ws_size,
                              hipStream_t stream)
{
    const float* x1 = (const float*)d_in[0];
    const float* x2 = (const float*)d_in[1];
    const float* wr = (const float*)d_in[2];
    const float* gA = (const float*)d_in[3];
    const float* bA = (const float*)d_in[4];
    const float* w1 = (const float*)d_in[5];
    const float* g1 = (const float*)d_in[6];
    const float* b1 = (const float*)d_in[7];
    const float* w2 = (const float*)d_in[8];
    const float* g2 = (const float*)d_in[9];
    const float* b2 = (const float*)d_in[10];
    const int* sidx = (const int*)d_in[11];
    const int* uidx = (const int*)d_in[12];
    const int* nbr  = (const int*)d_in[13];

    // ws (~72.3 MB): x2t bf16 51.2MB (h2 aliases it after conv1) | y bf16 8.19MB |
    // coarseN bf16 12.8MB | stats tail. h1 bf16 [B][Nf][32] = 51.2MB in d_out's
    // lower half; weight-fragment tables in d_out's upper half (dead until k_norm2
    // overwrites the whole output at the end).
    char* ws = (char*)d_ws;
    u16* x2t     = (u16*)ws;
    u16* h2      = (u16*)ws;                            // alias: x2t dead after conv1
    u16* y       = (u16*)(ws + 51200000);
    u16* coarseN = (u16*)(ws + 59392000);
    float* statsA = (float*)(ws + 72192000);            // 3 x 16 KB padded accumulators
    float* stats1 = (float*)(ws + 72192000 + 16384);
    float* stats2 = (float*)(ws + 72192000 + 32768);
    float* ssA    = (float*)(ws + 72192000 + 49152);    // 3 x 512 B scale/shift tables
    float* ss1    = (float*)(ws + 72192000 + 49664);
    float* ss2    = (float*)(ws + 72192000 + 50176);
    u16* h1  = (u16*)d_out;                             // d_out lower half as bf16 scratch
    u16* wf1g = (u16*)((char*)d_out + 96000000);        // 28672 B, dead before k_norm2
    u16* wf2g = (u16*)((char*)d_out + 96000000 + 28672);// 14336 B

    k_zero<<<48, 256, 0, stream>>>(statsA, 12288);
    k_wprep<<<1, 256, 0, stream>>>(w1, w2, wf1g, wf2g);
    k_x2t<<<dim3(6250, BB), 256, 0, stream>>>(x2, x2t);
    k_reduce<<<dim3(125, BB), 256, 0, stream>>>(x1, wr, y);
    k_statsB<<<dim3(125, BB), 256, 0, stream>>>(y, statsA, SVOX);
    k_fin<<<1, 64, 0, stream>>>(statsA, gA, bA, ssA, 1.f / SVOX);
    k_coarse<<<dim3(391, BB), 256, 0, stream>>>(y, ssA, sidx, coarseN);
    k_conv1<<<dim3(3125, BB), 512, 0, stream>>>(x2t, coarseN, wf1g, uidx, nbr, h1);
    k_statsB<<<dim3(782, BB), 256, 0, stream>>>(h1, stats1, NF);
    k_fin<<<1, 64, 0, stream>>>(stats1, g1, b1, ss1, 1.f / NF);
    k_conv2<<<dim3(3125, BB), 512, 0, stream>>>(h1, wf2g, nbr, ss1, h2);
    k_statsB<<<dim3(782, BB), 256, 0, stream>>>(h2, stats2, NF);
    k_fin<<<1, 64, 0, stream>>>(stats2, g2, b2, ss2, 1.f / NF);
    k_norm2<<<dim3(6250, BB), 256, 0, stream>>>(h2, ss2, (float*)d_out);
}

// Round 4
// 581.411 us; speedup vs baseline: 2.0918x; 1.2020x over previous
//
#include <hip/hip_runtime.h>
#include <cstdint>

// FP32 external interface (reference is jnp.float32). Intermediates bf16 (u16),
// all accumulation fp32. R9: single merged 128-B gather record for conv1
// (comb[n] = {x2[n] 32ch | relu(norm(y[sidx[uidx[n]]])) 32ch}) halves random
// line-requests at constant bytes; GroupNorm stats fused into conv1/conv2 via
// shfl+LDS+global atomics; conv2 writes f32 transposed straight to d_out and
// k_norm2c normalizes in place. 14 -> 10 launches.

typedef unsigned short u16;
typedef u16 u16x8 __attribute__((ext_vector_type(8)));
typedef float f4 __attribute__((ext_vector_type(4)));
using s16x8 = __attribute__((ext_vector_type(8))) short;
using u16x4 = __attribute__((ext_vector_type(4))) u16;

#define EPS 1e-5f
#define BB 2
#define CIN 64
#define CH 32
#define SVOX 64000
#define NC 100000
#define NF 400000

static __device__ __forceinline__ float b2f(u16 h) {
    return __builtin_bit_cast(float, (unsigned)h << 16);
}
static __device__ __forceinline__ u16 f2b(float f) {
    unsigned u = __builtin_bit_cast(unsigned, f);
    u += 0x7FFFu + ((u >> 16) & 1u);
    return (u16)(u >> 16);
}
static __device__ __forceinline__ f4 mfma16(s16x8 a, s16x8 b, f4 c) {
    return __builtin_amdgcn_mfma_f32_16x16x32_bf16(a, b, c, 0, 0, 0);
}

// ---------------- prep: zero stats + build MFMA A-fragment weight tables -------
__global__ __launch_bounds__(256) void k_prep(
    const float* __restrict__ w1, const float* __restrict__ w2,
    float* __restrict__ stats, u16* __restrict__ wf1, u16* __restrict__ wf2)
{
    int tid = threadIdx.x;
    for (int i = tid; i < 12288; i += 256) stats[i] = 0.f;
    for (int i = tid; i < 14 * 2 * 512; i += 256) {
        int j = i & 7, l = (i >> 3) & 63, ot = (i >> 9) & 1, s = i >> 10;
        int k = s >> 1, h = s & 1;
        int c = h * 32 + (l >> 4) * 8 + j;
        int o = ot * 16 + (l & 15);
        wf1[i] = f2b(w1[(o * CIN + c) * 7 + k]);
    }
    for (int i = tid; i < 7 * 2 * 512; i += 256) {
        int j = i & 7, l = (i >> 3) & 63, ot = (i >> 9) & 1, k = i >> 10;
        int c = (l >> 4) * 8 + j;
        int o = ot * 16 + (l & 15);
        wf2[i] = f2b(w2[(o * CH + c) * 7 + k]);
    }
}

// ---------------- stage A: dense 1x1x1 conv (64 -> 32), y bf16 voxel-major ------
__global__ __launch_bounds__(256) void k_reduce(
    const float* __restrict__ x1, const float* __restrict__ wr,
    u16* __restrict__ y)
{
    __shared__ float wl[CIN * CH];
    int tid = threadIdx.x, b = blockIdx.y;
    for (int i = tid; i < CIN * CH; i += 256) {
        int c = i >> 5, o = i & 31;
        wl[i] = wr[o * CIN + c];   // wl[c][o]
    }
    __syncthreads();
    int s0 = blockIdx.x * 512 + tid;
    int s1 = s0 + 256;
    const float* xb = x1 + (size_t)b * CIN * SVOX;
    float acc0[CH], acc1[CH];
#pragma unroll
    for (int o = 0; o < CH; o++) { acc0[o] = 0.f; acc1[o] = 0.f; }
    for (int c = 0; c < CIN; c++) {
        float xv0 = xb[(size_t)c * SVOX + s0];
        float xv1 = xb[(size_t)c * SVOX + s1];
        const float* w = &wl[c * CH];
#pragma unroll
        for (int o = 0; o < CH; o++) {
            float wv = w[o];
            acc0[o] = fmaf(xv0, wv, acc0[o]);
            acc1[o] = fmaf(xv1, wv, acc1[o]);
        }
    }
    u16* y0 = y + ((size_t)b * SVOX + s0) * CH;
    u16* y1 = y + ((size_t)b * SVOX + s1) * CH;
#pragma unroll
    for (int g = 0; g < 4; g++) {
        u16x8 v0, v1;
#pragma unroll
        for (int i = 0; i < 8; i++) {
            v0[i] = f2b(acc0[g * 8 + i]);
            v1[i] = f2b(acc1[g * 8 + i]);
        }
        ((u16x8*)y0)[g] = v0;
        ((u16x8*)y1)[g] = v1;
    }
}

// ---------------- per-channel stats over rows, bf16 input [B][rows][32] ----------
__global__ __launch_bounds__(256) void k_statsB(
    const u16* __restrict__ x, float* __restrict__ stats, int rows)
{
    __shared__ float sred[CH * 2];
    int tid = threadIdx.x, b = blockIdx.y;
    if (tid < CH * 2) sred[tid] = 0.f;
    __syncthreads();
    int o = tid & 31, stripe = tid >> 5;
    const u16* xb = x + (size_t)b * rows * CH;
    int r0 = blockIdx.x * 512 + stripe * 64;
    float s = 0.f, q = 0.f;
    for (int i = 0; i < 64; i++) {
        int r = r0 + i;
        if (r < rows) {
            float v = b2f(xb[(size_t)r * CH + o]);
            s += v; q = fmaf(v, v, q);
        }
    }
    atomicAdd(&sred[o * 2], s);
    atomicAdd(&sred[o * 2 + 1], q);
    __syncthreads();
    if (tid < CH * 2) atomicAdd(&stats[(size_t)(b * CH * 2 + tid) * 32], sred[tid]);
}

// ---------------- finalize stats -> per-channel scale/shift ----------------
__global__ void k_fin(const float* __restrict__ stats, const float* __restrict__ gamma,
                      const float* __restrict__ beta, float* __restrict__ ss, float invN)
{
    int i = threadIdx.x;
    if (i >= BB * CH) return;
    float sum = stats[(size_t)(i * 2) * 32];
    float sq  = stats[(size_t)(i * 2 + 1) * 32];
    float mean = sum * invN;
    float var = sq * invN - mean * mean;
    float rstd = rsqrtf(var + EPS);
    int o = i & 31;
    float sc = rstd * gamma[o];
    ss[i * 2] = sc;
    ss[i * 2 + 1] = beta[o] - mean * sc;
}

// ---------------- build comb records [B][NF][64] bf16 (128 B each) -------------
// ch 0..31 = x2 (transposed), ch 32..63 = relu(norm(y[sidx[uidx[n]]])).
__global__ __launch_bounds__(256) void k_build(
    const float* __restrict__ x2, const u16* __restrict__ y,
    const float* __restrict__ ssA, const int* __restrict__ sidx,
    const int* __restrict__ uidx, u16* __restrict__ comb)
{
    __shared__ u16 tile[64][40];
    __shared__ float sl[CH * 2];
    int tid = threadIdx.x, b = blockIdx.y;
    int n0 = blockIdx.x * 64;
    if (tid < CH * 2) sl[tid] = ssA[b * CH * 2 + tid];
    int c = tid >> 3, no = (tid & 7) * 8;
    const float* src = x2 + ((size_t)b * CH + c) * NF + n0 + no;
    f4 v0 = *(const f4*)src;
    f4 v1 = *(const f4*)(src + 4);
#pragma unroll
    for (int i = 0; i < 4; i++) tile[no + i][c] = f2b(v0[i]);
#pragma unroll
    for (int i = 0; i < 4; i++) tile[no + 4 + i][c] = f2b(v1[i]);
    __syncthreads();
    int nl = tid >> 3, seg = tid & 7;
#pragma unroll
    for (int it = 0; it < 2; it++) {
        int n = n0 + it * 32 + nl;
        u16x8 ov;
        if (seg < 4) {
            int co = seg * 8;
#pragma unroll
            for (int i = 0; i < 8; i++) ov[i] = tile[it * 32 + nl][co + i];
        } else {
            int u = uidx[(size_t)b * NF + n];
            int j = sidx[(size_t)b * NC + u];
            const u16x8* yr = (const u16x8*)(y + ((size_t)b * SVOX + j) * CH);
            u16x8 v = yr[seg - 4];
            int co = (seg - 4) * 8;
#pragma unroll
            for (int i = 0; i < 8; i++)
                ov[i] = f2b(fmaxf(fmaf(b2f(v[i]), sl[(co + i) * 2], sl[(co + i) * 2 + 1]), 0.f));
        }
        *(u16x8*)(comb + ((size_t)b * NF + n) * 64 + seg * 8) = ov;
    }
}

// ---------------- conv1: MFMA gather-GEMM over 128-B comb records ---------------
// out[n][o] = sum_{k,c} comb[nbr[n][k]][c] * w1[o][c][k]; fused stats1.
__global__ __launch_bounds__(512) void k_conv1(
    const u16* __restrict__ comb, const u16* __restrict__ wfg,
    const int* __restrict__ nbr, u16* __restrict__ h1,
    float* __restrict__ stats1)
{
    __shared__ u16 wf[14 * 2 * 512];   // 28 KB shared by 8 waves
    __shared__ float sst[64];
    int tid = threadIdx.x, b = blockIdx.y;
    if (tid < 64) sst[tid] = 0.f;
    const f4* wsrc = (const f4*)wfg;
    f4* wdst = (f4*)wf;
    for (int i = tid; i < 1792; i += 512) wdst[i] = wsrc[i];
    __syncthreads();
    const s16x8* wfv = (const s16x8*)wf;
    int lane = tid & 63, wave = tid >> 6;
    int p = lane & 15, q = lane >> 4;
    int n = blockIdx.x * 128 + wave * 16 + p;   // grid exact: 3125*128 == NF
    const u16* Cb = comb + (size_t)b * NF * 64;
    const int* nbb = nbr + ((size_t)b * NF + n) * 7;
    int i0[7];
#pragma unroll
    for (int k = 0; k < 7; k++) i0[k] = nbb[k];
    s16x8 rlo[7], rhi[7];
#pragma unroll
    for (int k = 0; k < 7; k++) {
        const u16* rec = Cb + (size_t)i0[k] * 64;
        rlo[k] = __builtin_bit_cast(s16x8, *(const u16x8*)(rec + q * 8));
        rhi[k] = __builtin_bit_cast(s16x8, *(const u16x8*)(rec + 32 + q * 8));
    }
    f4 acc0 = {0.f, 0.f, 0.f, 0.f};
    f4 acc1 = {0.f, 0.f, 0.f, 0.f};
#pragma unroll
    for (int k = 0; k < 7; k++) {
        acc0 = mfma16(wfv[(k * 4 + 0) * 64 + lane], rlo[k], acc0);
        acc1 = mfma16(wfv[(k * 4 + 1) * 64 + lane], rlo[k], acc1);
        acc0 = mfma16(wfv[(k * 4 + 2) * 64 + lane], rhi[k], acc0);
        acc1 = mfma16(wfv[(k * 4 + 3) * 64 + lane], rhi[k], acc1);
    }
    // fused stats: reduce over the 16 particles (p) per channel, f32 pre-rounding
    float s[8], t[8];
#pragma unroll
    for (int r = 0; r < 4; r++) {
        s[r] = acc0[r];     t[r] = acc0[r] * acc0[r];
        s[4 + r] = acc1[r]; t[4 + r] = acc1[r] * acc1[r];
    }
#pragma unroll
    for (int m = 1; m < 16; m <<= 1) {
#pragma unroll
        for (int j = 0; j < 8; j++) {
            s[j] += __shfl_xor(s[j], m);
            t[j] += __shfl_xor(t[j], m);
        }
    }
    if (p == 0) {
#pragma unroll
        for (int r = 0; r < 4; r++) {
            atomicAdd(&sst[(q * 4 + r) * 2],       s[r]);
            atomicAdd(&sst[(q * 4 + r) * 2 + 1],   t[r]);
            atomicAdd(&sst[(16 + q * 4 + r) * 2],     s[4 + r]);
            atomicAdd(&sst[(16 + q * 4 + r) * 2 + 1], t[4 + r]);
        }
    }
    // D: col = lane&15 = particle, row = 4*q + r = output channel
    u16x4 v0, v1;
#pragma unroll
    for (int r = 0; r < 4; r++) { v0[r] = f2b(acc0[r]); v1[r] = f2b(acc1[r]); }
    u16* out = h1 + ((size_t)b * NF + n) * CH + q * 4;
    *(u16x4*)out = v0;
    *(u16x4*)(out + 16) = v1;
    __syncthreads();
    if (tid < 64) atomicAdd(&stats1[(size_t)(b * 64 + tid) * 32], sst[tid]);
}

// ---------------- conv2: gather-GEMM, norm1+relu fused, f32 transposed out ------
__global__ __launch_bounds__(512) void k_conv2(
    const u16* __restrict__ x, const u16* __restrict__ wfg,
    const int* __restrict__ nbr, const float* __restrict__ ss1,
    float* __restrict__ out, float* __restrict__ stats2)
{
    __shared__ u16 wf[7 * 2 * 512];   // 14 KB shared by 8 waves
    __shared__ float sst[64];
    int tid = threadIdx.x, b = blockIdx.y;
    if (tid < 64) sst[tid] = 0.f;
    const f4* wsrc = (const f4*)wfg;
    f4* wdst = (f4*)wf;
    for (int i = tid; i < 896; i += 512) wdst[i] = wsrc[i];
    __syncthreads();
    const s16x8* wfv = (const s16x8*)wf;
    int lane = tid & 63, wave = tid >> 6;
    int p = lane & 15, q = lane >> 4;
    int n = blockIdx.x * 128 + wave * 16 + p;
    const u16* Xb = x + (size_t)b * NF * CH;
    const int* nbb = nbr + ((size_t)b * NF + n) * 7;
    float sc[8], sh[8];
#pragma unroll
    for (int j = 0; j < 8; j++) {
        sc[j] = ss1[(b * CH + q * 8 + j) * 2];
        sh[j] = ss1[(b * CH + q * 8 + j) * 2 + 1];
    }
    int i0[7];
#pragma unroll
    for (int k = 0; k < 7; k++) i0[k] = nbb[k];
    u16x8 raw[7];
#pragma unroll
    for (int k = 0; k < 7; k++)
        raw[k] = *(const u16x8*)(Xb + (size_t)i0[k] * CH + q * 8);
    f4 acc0 = {0.f, 0.f, 0.f, 0.f};
    f4 acc1 = {0.f, 0.f, 0.f, 0.f};
#pragma unroll
    for (int k = 0; k < 7; k++) {
        u16x8 nv;
#pragma unroll
        for (int j = 0; j < 8; j++)
            nv[j] = f2b(fmaxf(fmaf(b2f(raw[k][j]), sc[j], sh[j]), 0.f));
        s16x8 a = __builtin_bit_cast(s16x8, nv);
        acc0 = mfma16(wfv[(k * 2 + 0) * 64 + lane], a, acc0);
        acc1 = mfma16(wfv[(k * 2 + 1) * 64 + lane], a, acc1);
    }
    // fused stats2 on raw f32 conv output
    float s[8], t[8];
#pragma unroll
    for (int r = 0; r < 4; r++) {
        s[r] = acc0[r];     t[r] = acc0[r] * acc0[r];
        s[4 + r] = acc1[r]; t[4 + r] = acc1[r] * acc1[r];
    }
#pragma unroll
    for (int m = 1; m < 16; m <<= 1) {
#pragma unroll
        for (int j = 0; j < 8; j++) {
            s[j] += __shfl_xor(s[j], m);
            t[j] += __shfl_xor(t[j], m);
        }
    }
    if (p == 0) {
#pragma unroll
        for (int r = 0; r < 4; r++) {
            atomicAdd(&sst[(q * 4 + r) * 2],       s[r]);
            atomicAdd(&sst[(q * 4 + r) * 2 + 1],   t[r]);
            atomicAdd(&sst[(16 + q * 4 + r) * 2],     s[4 + r]);
            atomicAdd(&sst[(16 + q * 4 + r) * 2 + 1], t[4 + r]);
        }
    }
    // f32 transposed store: out[b][ch][n]
    float* ob = out + (size_t)b * CH * NF + n;
#pragma unroll
    for (int r = 0; r < 4; r++) {
        ob[(size_t)(q * 4 + r) * NF] = acc0[r];
        ob[(size_t)(16 + q * 4 + r) * NF] = acc1[r];
    }
    __syncthreads();
    if (tid < 64) atomicAdd(&stats2[(size_t)(b * 64 + tid) * 32], sst[tid]);
}

// ---------------- in-place normalize+relu on f32 [B][32][NF] --------------------
__global__ __launch_bounds__(256) void k_norm2c(
    float* __restrict__ h, const float* __restrict__ ss)
{
    int i4 = blockIdx.x * 256 + threadIdx.x;    // 6,400,000 f4 elements total
    int cf = i4 / (NF / 4);                      // 0..63 = b*32 + c
    float sc = ss[cf * 2], sh = ss[cf * 2 + 1];
    f4 v = ((f4*)h)[i4];
#pragma unroll
    for (int j = 0; j < 4; j++) v[j] = fmaxf(fmaf(v[j], sc, sh), 0.f);
    ((f4*)h)[i4] = v;
}

extern "C" void kernel_launch(void* const* d_in, const int* in_sizes, int n_in,
                              void* d_out, int out_size, void* d_ws, size_t ws_size,
                              hipStream_t stream)
{
    const float* x1 = (const float*)d_in[0];
    const float* x2 = (const float*)d_in[1];
    const float* wr = (const float*)d_in[2];
    const float* gA = (const float*)d_in[3];
    const float* bA = (const float*)d_in[4];
    const float* w1 = (const float*)d_in[5];
    const float* g1 = (const float*)d_in[6];
    const float* b1 = (const float*)d_in[7];
    const float* w2 = (const float*)d_in[8];
    const float* g2 = (const float*)d_in[9];
    const float* b2 = (const float*)d_in[10];
    const int* sidx = (const int*)d_in[11];
    const int* uidx = (const int*)d_in[12];
    const int* nbr  = (const int*)d_in[13];

    // comb [B][NF][64] bf16 = 102.4 MB lives in d_out (dead before conv2 writes
    // f32 output there). ws (~59.5 MB): h1 51.2 | y 8.19 | stats | ss | wf tables.
    char* ws = (char*)d_ws;
    u16* h1      = (u16*)ws;                            // [B][NF][32] bf16
    u16* y       = (u16*)(ws + 51200000);               // [B][SVOX][32] bf16
    float* stats = (float*)(ws + 59392000);             // 3 x 16 KB padded accumulators
    float* statsA = stats;
    float* stats1 = (float*)(ws + 59392000 + 16384);
    float* stats2 = (float*)(ws + 59392000 + 32768);
    float* ssA    = (float*)(ws + 59392000 + 49152);    // 3 x 512 B scale/shift
    float* ss1    = (float*)(ws + 59392000 + 49664);
    float* ss2    = (float*)(ws + 59392000 + 50176);
    u16* wf1g = (u16*)(ws + 59392000 + 50688);          // 28672 B
    u16* wf2g = (u16*)(ws + 59392000 + 50688 + 28672);  // 14336 B
    u16* comb = (u16*)d_out;

    k_prep<<<1, 256, 0, stream>>>(w1, w2, stats, wf1g, wf2g);
    k_reduce<<<dim3(125, BB), 256, 0, stream>>>(x1, wr, y);
    k_statsB<<<dim3(125, BB), 256, 0, stream>>>(y, statsA, SVOX);
    k_fin<<<1, 64, 0, stream>>>(statsA, gA, bA, ssA, 1.f / SVOX);
    k_build<<<dim3(6250, BB), 256, 0, stream>>>(x2, y, ssA, sidx, uidx, comb);
    k_conv1<<<dim3(3125, BB), 512, 0, stream>>>(comb, wf1g, nbr, h1, stats1);
    k_fin<<<1, 64, 0, stream>>>(stats1, g1, b1, ss1, 1.f / NF);
    k_conv2<<<dim3(3125, BB), 512, 0, stream>>>(h1, wf2g, nbr, ss1, (float*)d_out, stats2);
    k_fin<<<1, 64, 0, stream>>>(stats2, g2, b2, ss2, 1.f / NF);
    k_norm2c<<<25000, 256, 0, stream>>>((float*)d_out, ss2);
}

// Round 5
// 560.782 us; speedup vs baseline: 2.1688x; 1.0368x over previous
//
#include <hip/hip_runtime.h>
#include <cstdint>

// FP32 external interface (reference is jnp.float32). Intermediates bf16 (u16),
// all accumulation fp32. R10: consolidation. Convs are at the random-gather
// line-service roofline (~45G 128-B lines/s); this round removes the remaining
// small kernels: statsA fused into k_reduce (butterfly+atomics), all three
// k_fin folded into their consumers (k_build / k_conv2 / k_norm2c).
// 10 -> 6 launches.

typedef unsigned short u16;
typedef u16 u16x8 __attribute__((ext_vector_type(8)));
typedef float f4 __attribute__((ext_vector_type(4)));
using s16x8 = __attribute__((ext_vector_type(8))) short;
using u16x4 = __attribute__((ext_vector_type(4))) u16;

#define EPS 1e-5f
#define BB 2
#define CIN 64
#define CH 32
#define SVOX 64000
#define NC 100000
#define NF 400000

static __device__ __forceinline__ float b2f(u16 h) {
    return __builtin_bit_cast(float, (unsigned)h << 16);
}
static __device__ __forceinline__ u16 f2b(float f) {
    unsigned u = __builtin_bit_cast(unsigned, f);
    u += 0x7FFFu + ((u >> 16) & 1u);
    return (u16)(u >> 16);
}
static __device__ __forceinline__ f4 mfma16(s16x8 a, s16x8 b, f4 c) {
    return __builtin_amdgcn_mfma_f32_16x16x32_bf16(a, b, c, 0, 0, 0);
}

// ---------------- prep: zero stats + build MFMA A-fragment weight tables -------
__global__ __launch_bounds__(256) void k_prep(
    const float* __restrict__ w1, const float* __restrict__ w2,
    float* __restrict__ stats, u16* __restrict__ wf1, u16* __restrict__ wf2)
{
    int tid = threadIdx.x;
    for (int i = tid; i < 12288; i += 256) stats[i] = 0.f;
    for (int i = tid; i < 14 * 2 * 512; i += 256) {
        int j = i & 7, l = (i >> 3) & 63, ot = (i >> 9) & 1, s = i >> 10;
        int k = s >> 1, h = s & 1;
        int c = h * 32 + (l >> 4) * 8 + j;
        int o = ot * 16 + (l & 15);
        wf1[i] = f2b(w1[(o * CIN + c) * 7 + k]);
    }
    for (int i = tid; i < 7 * 2 * 512; i += 256) {
        int j = i & 7, l = (i >> 3) & 63, ot = (i >> 9) & 1, k = i >> 10;
        int c = (l >> 4) * 8 + j;
        int o = ot * 16 + (l & 15);
        wf2[i] = f2b(w2[(o * CH + c) * 7 + k]);
    }
}

// ---------------- stage A: dense 1x1x1 conv (64 -> 32) + fused GN stats --------
__global__ __launch_bounds__(256) void k_reduce(
    const float* __restrict__ x1, const float* __restrict__ wr,
    u16* __restrict__ y, float* __restrict__ statsA)
{
    __shared__ float wl[CIN * CH];
    __shared__ float sred[64];
    int tid = threadIdx.x, b = blockIdx.y;
    if (tid < 64) sred[tid] = 0.f;
    for (int i = tid; i < CIN * CH; i += 256) {
        int c = i >> 5, o = i & 31;
        wl[i] = wr[o * CIN + c];   // wl[c][o]
    }
    __syncthreads();
    int s0 = blockIdx.x * 512 + tid;
    int s1 = s0 + 256;
    const float* xb = x1 + (size_t)b * CIN * SVOX;
    float acc0[CH], acc1[CH];
#pragma unroll
    for (int o = 0; o < CH; o++) { acc0[o] = 0.f; acc1[o] = 0.f; }
    for (int c = 0; c < CIN; c++) {
        float xv0 = xb[(size_t)c * SVOX + s0];
        float xv1 = xb[(size_t)c * SVOX + s1];
        const float* w = &wl[c * CH];
#pragma unroll
        for (int o = 0; o < CH; o++) {
            float wv = w[o];
            acc0[o] = fmaf(xv0, wv, acc0[o]);
            acc1[o] = fmaf(xv1, wv, acc1[o]);
        }
    }
    u16* y0 = y + ((size_t)b * SVOX + s0) * CH;
    u16* y1 = y + ((size_t)b * SVOX + s1) * CH;
#pragma unroll
    for (int g = 0; g < 4; g++) {
        u16x8 v0, v1;
#pragma unroll
        for (int i = 0; i < 8; i++) {
            v0[i] = f2b(acc0[g * 8 + i]);
            v1[i] = f2b(acc1[g * 8 + i]);
        }
        ((u16x8*)y0)[g] = v0;
        ((u16x8*)y1)[g] = v1;
    }
    // fused stats: wave butterfly per 8-channel group, then LDS + global atomics
    int lane = tid & 63;
#pragma unroll
    for (int g = 0; g < 4; g++) {
        float s[8], qq[8];
#pragma unroll
        for (int i = 0; i < 8; i++) {
            int o = g * 8 + i;
            s[i] = acc0[o] + acc1[o];
            qq[i] = fmaf(acc0[o], acc0[o], acc1[o] * acc1[o]);
        }
#pragma unroll
        for (int m = 1; m < 64; m <<= 1) {
#pragma unroll
            for (int i = 0; i < 8; i++) {
                s[i] += __shfl_xor(s[i], m);
                qq[i] += __shfl_xor(qq[i], m);
            }
        }
        if (lane == 0) {
#pragma unroll
            for (int i = 0; i < 8; i++) {
                atomicAdd(&sred[(g * 8 + i) * 2], s[i]);
                atomicAdd(&sred[(g * 8 + i) * 2 + 1], qq[i]);
            }
        }
    }
    __syncthreads();
    if (tid < 64) atomicAdd(&statsA[(size_t)(b * 64 + tid) * 32], sred[tid]);
}

// ---------------- build comb records [B][NF][64] bf16 (128 B each) -------------
// ch 0..31 = x2 (transposed), ch 32..63 = relu(norm(y[sidx[uidx[n]]])).
// GN-A finalize folded in (reads raw statsA + gamma/beta per block).
__global__ __launch_bounds__(256) void k_build(
    const float* __restrict__ x2, const u16* __restrict__ y,
    const float* __restrict__ statsA, const float* __restrict__ gA,
    const float* __restrict__ bA, const int* __restrict__ sidx,
    const int* __restrict__ uidx, u16* __restrict__ comb)
{
    __shared__ u16 tile[64][40];
    __shared__ float sl[CH * 2];
    int tid = threadIdx.x, b = blockIdx.y;
    int n0 = blockIdx.x * 64;
    if (tid < CH) {
        float sum = statsA[(size_t)(b * 64 + tid * 2) * 32];
        float sq  = statsA[(size_t)(b * 64 + tid * 2 + 1) * 32];
        float mean = sum * (1.f / SVOX);
        float var = sq * (1.f / SVOX) - mean * mean;
        float sc = rsqrtf(var + EPS) * gA[tid];
        sl[tid * 2] = sc;
        sl[tid * 2 + 1] = bA[tid] - mean * sc;
    }
    int c = tid >> 3, no = (tid & 7) * 8;
    const float* src = x2 + ((size_t)b * CH + c) * NF + n0 + no;
    f4 v0 = *(const f4*)src;
    f4 v1 = *(const f4*)(src + 4);
#pragma unroll
    for (int i = 0; i < 4; i++) tile[no + i][c] = f2b(v0[i]);
#pragma unroll
    for (int i = 0; i < 4; i++) tile[no + 4 + i][c] = f2b(v1[i]);
    __syncthreads();
    int nl = tid >> 3, seg = tid & 7;
#pragma unroll
    for (int it = 0; it < 2; it++) {
        int n = n0 + it * 32 + nl;
        u16x8 ov;
        if (seg < 4) {
            int co = seg * 8;
#pragma unroll
            for (int i = 0; i < 8; i++) ov[i] = tile[it * 32 + nl][co + i];
        } else {
            int u = uidx[(size_t)b * NF + n];
            int j = sidx[(size_t)b * NC + u];
            const u16x8* yr = (const u16x8*)(y + ((size_t)b * SVOX + j) * CH);
            u16x8 v = yr[seg - 4];
            int co = (seg - 4) * 8;
#pragma unroll
            for (int i = 0; i < 8; i++)
                ov[i] = f2b(fmaxf(fmaf(b2f(v[i]), sl[(co + i) * 2], sl[(co + i) * 2 + 1]), 0.f));
        }
        *(u16x8*)(comb + ((size_t)b * NF + n) * 64 + seg * 8) = ov;
    }
}

// ---------------- conv1: MFMA gather-GEMM over 128-B comb records ---------------
// out[n][o] = sum_{k,c} comb[nbr[n][k]][c] * w1[o][c][k]; fused stats1.
__global__ __launch_bounds__(512) void k_conv1(
    const u16* __restrict__ comb, const u16* __restrict__ wfg,
    const int* __restrict__ nbr, u16* __restrict__ h1,
    float* __restrict__ stats1)
{
    __shared__ u16 wf[14 * 2 * 512];   // 28 KB shared by 8 waves
    __shared__ float sst[64];
    int tid = threadIdx.x, b = blockIdx.y;
    if (tid < 64) sst[tid] = 0.f;
    const f4* wsrc = (const f4*)wfg;
    f4* wdst = (f4*)wf;
    for (int i = tid; i < 1792; i += 512) wdst[i] = wsrc[i];
    __syncthreads();
    const s16x8* wfv = (const s16x8*)wf;
    int lane = tid & 63, wave = tid >> 6;
    int p = lane & 15, q = lane >> 4;
    int n = blockIdx.x * 128 + wave * 16 + p;   // grid exact: 3125*128 == NF
    const u16* Cb = comb + (size_t)b * NF * 64;
    const int* nbb = nbr + ((size_t)b * NF + n) * 7;
    int i0[7];
#pragma unroll
    for (int k = 0; k < 7; k++) i0[k] = nbb[k];
    s16x8 rlo[7], rhi[7];
#pragma unroll
    for (int k = 0; k < 7; k++) {
        const u16* rec = Cb + (size_t)i0[k] * 64;
        rlo[k] = __builtin_bit_cast(s16x8, *(const u16x8*)(rec + q * 8));
        rhi[k] = __builtin_bit_cast(s16x8, *(const u16x8*)(rec + 32 + q * 8));
    }
    f4 acc0 = {0.f, 0.f, 0.f, 0.f};
    f4 acc1 = {0.f, 0.f, 0.f, 0.f};
#pragma unroll
    for (int k = 0; k < 7; k++) {
        acc0 = mfma16(wfv[(k * 4 + 0) * 64 + lane], rlo[k], acc0);
        acc1 = mfma16(wfv[(k * 4 + 1) * 64 + lane], rlo[k], acc1);
        acc0 = mfma16(wfv[(k * 4 + 2) * 64 + lane], rhi[k], acc0);
        acc1 = mfma16(wfv[(k * 4 + 3) * 64 + lane], rhi[k], acc1);
    }
    // fused stats: reduce over the 16 particles (p) per channel, f32 pre-rounding
    float s[8], t[8];
#pragma unroll
    for (int r = 0; r < 4; r++) {
        s[r] = acc0[r];     t[r] = acc0[r] * acc0[r];
        s[4 + r] = acc1[r]; t[4 + r] = acc1[r] * acc1[r];
    }
#pragma unroll
    for (int m = 1; m < 16; m <<= 1) {
#pragma unroll
        for (int j = 0; j < 8; j++) {
            s[j] += __shfl_xor(s[j], m);
            t[j] += __shfl_xor(t[j], m);
        }
    }
    if (p == 0) {
#pragma unroll
        for (int r = 0; r < 4; r++) {
            atomicAdd(&sst[(q * 4 + r) * 2],       s[r]);
            atomicAdd(&sst[(q * 4 + r) * 2 + 1],   t[r]);
            atomicAdd(&sst[(16 + q * 4 + r) * 2],     s[4 + r]);
            atomicAdd(&sst[(16 + q * 4 + r) * 2 + 1], t[4 + r]);
        }
    }
    // D: col = lane&15 = particle, row = 4*q + r = output channel
    u16x4 v0, v1;
#pragma unroll
    for (int r = 0; r < 4; r++) { v0[r] = f2b(acc0[r]); v1[r] = f2b(acc1[r]); }
    u16* out = h1 + ((size_t)b * NF + n) * CH + q * 4;
    *(u16x4*)out = v0;
    *(u16x4*)(out + 16) = v1;
    __syncthreads();
    if (tid < 64) atomicAdd(&stats1[(size_t)(b * 64 + tid) * 32], sst[tid]);
}

// ---------------- conv2: gather-GEMM, fin1+norm1+relu fused, f32 out ------------
__global__ __launch_bounds__(512) void k_conv2(
    const u16* __restrict__ x, const u16* __restrict__ wfg,
    const int* __restrict__ nbr, const float* __restrict__ stats1,
    const float* __restrict__ g1, const float* __restrict__ b1,
    float* __restrict__ out, float* __restrict__ stats2)
{
    __shared__ u16 wf[7 * 2 * 512];   // 14 KB shared by 8 waves
    __shared__ float sst[64];
    __shared__ float sl1[64];
    int tid = threadIdx.x, b = blockIdx.y;
    if (tid < 64) sst[tid] = 0.f;
    const f4* wsrc = (const f4*)wfg;
    f4* wdst = (f4*)wf;
    for (int i = tid; i < 896; i += 512) wdst[i] = wsrc[i];
    if (tid < CH) {
        float sum = stats1[(size_t)(b * 64 + tid * 2) * 32];
        float sq  = stats1[(size_t)(b * 64 + tid * 2 + 1) * 32];
        float mean = sum * (1.f / NF);
        float var = sq * (1.f / NF) - mean * mean;
        float sc = rsqrtf(var + EPS) * g1[tid];
        sl1[tid * 2] = sc;
        sl1[tid * 2 + 1] = b1[tid] - mean * sc;
    }
    __syncthreads();
    const s16x8* wfv = (const s16x8*)wf;
    int lane = tid & 63, wave = tid >> 6;
    int p = lane & 15, q = lane >> 4;
    int n = blockIdx.x * 128 + wave * 16 + p;
    const u16* Xb = x + (size_t)b * NF * CH;
    const int* nbb = nbr + ((size_t)b * NF + n) * 7;
    float sc[8], sh[8];
#pragma unroll
    for (int j = 0; j < 8; j++) {
        sc[j] = sl1[(q * 8 + j) * 2];
        sh[j] = sl1[(q * 8 + j) * 2 + 1];
    }
    int i0[7];
#pragma unroll
    for (int k = 0; k < 7; k++) i0[k] = nbb[k];
    u16x8 raw[7];
#pragma unroll
    for (int k = 0; k < 7; k++)
        raw[k] = *(const u16x8*)(Xb + (size_t)i0[k] * CH + q * 8);
    f4 acc0 = {0.f, 0.f, 0.f, 0.f};
    f4 acc1 = {0.f, 0.f, 0.f, 0.f};
#pragma unroll
    for (int k = 0; k < 7; k++) {
        u16x8 nv;
#pragma unroll
        for (int j = 0; j < 8; j++)
            nv[j] = f2b(fmaxf(fmaf(b2f(raw[k][j]), sc[j], sh[j]), 0.f));
        s16x8 a = __builtin_bit_cast(s16x8, nv);
        acc0 = mfma16(wfv[(k * 2 + 0) * 64 + lane], a, acc0);
        acc1 = mfma16(wfv[(k * 2 + 1) * 64 + lane], a, acc1);
    }
    // fused stats2 on raw f32 conv output
    float s[8], t[8];
#pragma unroll
    for (int r = 0; r < 4; r++) {
        s[r] = acc0[r];     t[r] = acc0[r] * acc0[r];
        s[4 + r] = acc1[r]; t[4 + r] = acc1[r] * acc1[r];
    }
#pragma unroll
    for (int m = 1; m < 16; m <<= 1) {
#pragma unroll
        for (int j = 0; j < 8; j++) {
            s[j] += __shfl_xor(s[j], m);
            t[j] += __shfl_xor(t[j], m);
        }
    }
    if (p == 0) {
#pragma unroll
        for (int r = 0; r < 4; r++) {
            atomicAdd(&sst[(q * 4 + r) * 2],       s[r]);
            atomicAdd(&sst[(q * 4 + r) * 2 + 1],   t[r]);
            atomicAdd(&sst[(16 + q * 4 + r) * 2],     s[4 + r]);
            atomicAdd(&sst[(16 + q * 4 + r) * 2 + 1], t[4 + r]);
        }
    }
    // f32 transposed store: out[b][ch][n]
    float* ob = out + (size_t)b * CH * NF + n;
#pragma unroll
    for (int r = 0; r < 4; r++) {
        ob[(size_t)(q * 4 + r) * NF] = acc0[r];
        ob[(size_t)(16 + q * 4 + r) * NF] = acc1[r];
    }
    __syncthreads();
    if (tid < 64) atomicAdd(&stats2[(size_t)(b * 64 + tid) * 32], sst[tid]);
}

// ---------------- in-place fin2+normalize+relu on f32 [B][32][NF] ---------------
__global__ __launch_bounds__(256) void k_norm2c(
    float* __restrict__ h, const float* __restrict__ stats2,
    const float* __restrict__ g2, const float* __restrict__ b2)
{
    int i4 = blockIdx.x * 256 + threadIdx.x;    // 6,400,000 f4 elements total
    int cf = i4 / (NF / 4);                      // 0..63 = b*32 + c
    int o = cf & 31;
    float sum = stats2[(size_t)(cf * 2) * 32];
    float sq  = stats2[(size_t)(cf * 2 + 1) * 32];
    float mean = sum * (1.f / NF);
    float var = sq * (1.f / NF) - mean * mean;
    float sc = rsqrtf(var + EPS) * g2[o];
    float sh = b2[o] - mean * sc;
    f4 v = ((f4*)h)[i4];
#pragma unroll
    for (int j = 0; j < 4; j++) v[j] = fmaxf(fmaf(v[j], sc, sh), 0.f);
    ((f4*)h)[i4] = v;
}

extern "C" void kernel_launch(void* const* d_in, const int* in_sizes, int n_in,
                              void* d_out, int out_size, void* d_ws, size_t ws_size,
                              hipStream_t stream)
{
    const float* x1 = (const float*)d_in[0];
    const float* x2 = (const float*)d_in[1];
    const float* wr = (const float*)d_in[2];
    const float* gA = (const float*)d_in[3];
    const float* bA = (const float*)d_in[4];
    const float* w1 = (const float*)d_in[5];
    const float* g1 = (const float*)d_in[6];
    const float* b1 = (const float*)d_in[7];
    const float* w2 = (const float*)d_in[8];
    const float* g2 = (const float*)d_in[9];
    const float* b2 = (const float*)d_in[10];
    const int* sidx = (const int*)d_in[11];
    const int* uidx = (const int*)d_in[12];
    const int* nbr  = (const int*)d_in[13];

    // comb [B][NF][64] bf16 = 102.4 MB lives in d_out (dead before conv2 writes
    // f32 output there). ws (~59.5 MB): h1 51.2 | y 8.19 | stats | wf tables.
    char* ws = (char*)d_ws;
    u16* h1      = (u16*)ws;                            // [B][NF][32] bf16
    u16* y       = (u16*)(ws + 51200000);               // [B][SVOX][32] bf16
    float* stats = (float*)(ws + 59392000);             // 3 x 16 KB padded accumulators
    float* statsA = stats;
    float* stats1 = (float*)(ws + 59392000 + 16384);
    float* stats2 = (float*)(ws + 59392000 + 32768);
    u16* wf1g = (u16*)(ws + 59392000 + 49152);          // 28672 B
    u16* wf2g = (u16*)(ws + 59392000 + 49152 + 28672);  // 14336 B
    u16* comb = (u16*)d_out;

    k_prep<<<1, 256, 0, stream>>>(w1, w2, stats, wf1g, wf2g);
    k_reduce<<<dim3(125, BB), 256, 0, stream>>>(x1, wr, y, statsA);
    k_build<<<dim3(6250, BB), 256, 0, stream>>>(x2, y, statsA, gA, bA, sidx, uidx, comb);
    k_conv1<<<dim3(3125, BB), 512, 0, stream>>>(comb, wf1g, nbr, h1, stats1);
    k_conv2<<<dim3(3125, BB), 512, 0, stream>>>(h1, wf2g, nbr, stats1, g1, b1, (float*)d_out, stats2);
    k_norm2c<<<25000, 256, 0, stream>>>((float*)d_out, stats2, g2, b2);
}

// Round 6
// 550.642 us; speedup vs baseline: 2.2087x; 1.0184x over previous
//
#include <hip/hip_runtime.h>
#include <cstdint>

// FP32 external interface (reference is jnp.float32). Intermediates bf16 (u16),
// all accumulation fp32. R11: grid-stride restructure of the streaming kernels
// (k_build 12500->1024*BB wgs, k_norm2c 25000->2048 wgs) per G11 -- testing the
// theory that workgroup-dispatch volume is the hidden ~300us sink; conv2's
// GroupNorm finalize moved from wave-0+LDS (serial block head) to per-lane
// registers. Convs themselves untouched (at the random-line-service roofline).

typedef unsigned short u16;
typedef u16 u16x8 __attribute__((ext_vector_type(8)));
typedef float f4 __attribute__((ext_vector_type(4)));
using s16x8 = __attribute__((ext_vector_type(8))) short;
using u16x4 = __attribute__((ext_vector_type(4))) u16;

#define EPS 1e-5f
#define BB 2
#define CIN 64
#define CH 32
#define SVOX 64000
#define NC 100000
#define NF 400000

static __device__ __forceinline__ float b2f(u16 h) {
    return __builtin_bit_cast(float, (unsigned)h << 16);
}
static __device__ __forceinline__ u16 f2b(float f) {
    unsigned u = __builtin_bit_cast(unsigned, f);
    u += 0x7FFFu + ((u >> 16) & 1u);
    return (u16)(u >> 16);
}
static __device__ __forceinline__ f4 mfma16(s16x8 a, s16x8 b, f4 c) {
    return __builtin_amdgcn_mfma_f32_16x16x32_bf16(a, b, c, 0, 0, 0);
}

// ---------------- prep: zero stats + build MFMA A-fragment weight tables -------
__global__ __launch_bounds__(256) void k_prep(
    const float* __restrict__ w1, const float* __restrict__ w2,
    float* __restrict__ stats, u16* __restrict__ wf1, u16* __restrict__ wf2)
{
    int tid = threadIdx.x;
    for (int i = tid; i < 12288; i += 256) stats[i] = 0.f;
    for (int i = tid; i < 14 * 2 * 512; i += 256) {
        int j = i & 7, l = (i >> 3) & 63, ot = (i >> 9) & 1, s = i >> 10;
        int k = s >> 1, h = s & 1;
        int c = h * 32 + (l >> 4) * 8 + j;
        int o = ot * 16 + (l & 15);
        wf1[i] = f2b(w1[(o * CIN + c) * 7 + k]);
    }
    for (int i = tid; i < 7 * 2 * 512; i += 256) {
        int j = i & 7, l = (i >> 3) & 63, ot = (i >> 9) & 1, k = i >> 10;
        int c = (l >> 4) * 8 + j;
        int o = ot * 16 + (l & 15);
        wf2[i] = f2b(w2[(o * CH + c) * 7 + k]);
    }
}

// ---------------- stage A: dense 1x1x1 conv (64 -> 32) + fused GN stats --------
__global__ __launch_bounds__(256) void k_reduce(
    const float* __restrict__ x1, const float* __restrict__ wr,
    u16* __restrict__ y, float* __restrict__ statsA)
{
    __shared__ float wl[CIN * CH];
    __shared__ float sred[64];
    int tid = threadIdx.x, b = blockIdx.y;
    if (tid < 64) sred[tid] = 0.f;
    for (int i = tid; i < CIN * CH; i += 256) {
        int c = i >> 5, o = i & 31;
        wl[i] = wr[o * CIN + c];   // wl[c][o]
    }
    __syncthreads();
    int s0 = blockIdx.x * 512 + tid;
    int s1 = s0 + 256;
    const float* xb = x1 + (size_t)b * CIN * SVOX;
    float acc0[CH], acc1[CH];
#pragma unroll
    for (int o = 0; o < CH; o++) { acc0[o] = 0.f; acc1[o] = 0.f; }
    for (int c = 0; c < CIN; c++) {
        float xv0 = xb[(size_t)c * SVOX + s0];
        float xv1 = xb[(size_t)c * SVOX + s1];
        const float* w = &wl[c * CH];
#pragma unroll
        for (int o = 0; o < CH; o++) {
            float wv = w[o];
            acc0[o] = fmaf(xv0, wv, acc0[o]);
            acc1[o] = fmaf(xv1, wv, acc1[o]);
        }
    }
    u16* y0 = y + ((size_t)b * SVOX + s0) * CH;
    u16* y1 = y + ((size_t)b * SVOX + s1) * CH;
#pragma unroll
    for (int g = 0; g < 4; g++) {
        u16x8 v0, v1;
#pragma unroll
        for (int i = 0; i < 8; i++) {
            v0[i] = f2b(acc0[g * 8 + i]);
            v1[i] = f2b(acc1[g * 8 + i]);
        }
        ((u16x8*)y0)[g] = v0;
        ((u16x8*)y1)[g] = v1;
    }
    // fused stats: wave butterfly per 8-channel group, then LDS + global atomics
    int lane = tid & 63;
#pragma unroll
    for (int g = 0; g < 4; g++) {
        float s[8], qq[8];
#pragma unroll
        for (int i = 0; i < 8; i++) {
            int o = g * 8 + i;
            s[i] = acc0[o] + acc1[o];
            qq[i] = fmaf(acc0[o], acc0[o], acc1[o] * acc1[o]);
        }
#pragma unroll
        for (int m = 1; m < 64; m <<= 1) {
#pragma unroll
            for (int i = 0; i < 8; i++) {
                s[i] += __shfl_xor(s[i], m);
                qq[i] += __shfl_xor(qq[i], m);
            }
        }
        if (lane == 0) {
#pragma unroll
            for (int i = 0; i < 8; i++) {
                atomicAdd(&sred[(g * 8 + i) * 2], s[i]);
                atomicAdd(&sred[(g * 8 + i) * 2 + 1], qq[i]);
            }
        }
    }
    __syncthreads();
    if (tid < 64) atomicAdd(&statsA[(size_t)(b * 64 + tid) * 32], sred[tid]);
}

// ---------------- build comb records [B][NF][64] bf16 (128 B each) -------------
// ch 0..31 = x2 (transposed), ch 32..63 = relu(norm(y[sidx[uidx[n]]])).
// Grid-stride over the 6250 64-particle tiles; x2 loads issued before the
// loop-top barrier so HBM latency overlaps the previous tile's phase 2.
__global__ __launch_bounds__(256) void k_build(
    const float* __restrict__ x2, const u16* __restrict__ y,
    const float* __restrict__ statsA, const float* __restrict__ gA,
    const float* __restrict__ bA, const int* __restrict__ sidx,
    const int* __restrict__ uidx, u16* __restrict__ comb)
{
    __shared__ u16 tile[64][40];
    __shared__ float sl[CH * 2];
    int tid = threadIdx.x, b = blockIdx.y;
    if (tid < CH) {
        float sum = statsA[(size_t)(b * 64 + tid * 2) * 32];
        float sq  = statsA[(size_t)(b * 64 + tid * 2 + 1) * 32];
        float mean = sum * (1.f / SVOX);
        float var = sq * (1.f / SVOX) - mean * mean;
        float sc = rsqrtf(var + EPS) * gA[tid];
        sl[tid * 2] = sc;
        sl[tid * 2 + 1] = bA[tid] - mean * sc;
    }
    int c = tid >> 3, no = (tid & 7) * 8;
    int nl = tid >> 3, seg = tid & 7;
    for (int t = blockIdx.x; t < 6250; t += gridDim.x) {
        int n0 = t * 64;
        const float* src = x2 + ((size_t)b * CH + c) * NF + n0 + no;
        f4 v0 = *(const f4*)src;
        f4 v1 = *(const f4*)(src + 4);
        __syncthreads();   // previous tile's phase-2 readers done (also: sl ready)
#pragma unroll
        for (int i = 0; i < 4; i++) tile[no + i][c] = f2b(v0[i]);
#pragma unroll
        for (int i = 0; i < 4; i++) tile[no + 4 + i][c] = f2b(v1[i]);
        __syncthreads();
#pragma unroll
        for (int it = 0; it < 2; it++) {
            int n = n0 + it * 32 + nl;
            u16x8 ov;
            if (seg < 4) {
                int co = seg * 8;
#pragma unroll
                for (int i = 0; i < 8; i++) ov[i] = tile[it * 32 + nl][co + i];
            } else {
                int u = uidx[(size_t)b * NF + n];
                int j = sidx[(size_t)b * NC + u];
                const u16x8* yr = (const u16x8*)(y + ((size_t)b * SVOX + j) * CH);
                u16x8 v = yr[seg - 4];
                int co = (seg - 4) * 8;
#pragma unroll
                for (int i = 0; i < 8; i++)
                    ov[i] = f2b(fmaxf(fmaf(b2f(v[i]), sl[(co + i) * 2], sl[(co + i) * 2 + 1]), 0.f));
            }
            *(u16x8*)(comb + ((size_t)b * NF + n) * 64 + seg * 8) = ov;
        }
    }
}

// ---------------- conv1: MFMA gather-GEMM over 128-B comb records ---------------
// out[n][o] = sum_{k,c} comb[nbr[n][k]][c] * w1[o][c][k]; fused stats1.
__global__ __launch_bounds__(512) void k_conv1(
    const u16* __restrict__ comb, const u16* __restrict__ wfg,
    const int* __restrict__ nbr, u16* __restrict__ h1,
    float* __restrict__ stats1)
{
    __shared__ u16 wf[14 * 2 * 512];   // 28 KB shared by 8 waves
    __shared__ float sst[64];
    int tid = threadIdx.x, b = blockIdx.y;
    if (tid < 64) sst[tid] = 0.f;
    const f4* wsrc = (const f4*)wfg;
    f4* wdst = (f4*)wf;
    for (int i = tid; i < 1792; i += 512) wdst[i] = wsrc[i];
    __syncthreads();
    const s16x8* wfv = (const s16x8*)wf;
    int lane = tid & 63, wave = tid >> 6;
    int p = lane & 15, q = lane >> 4;
    int n = blockIdx.x * 128 + wave * 16 + p;   // grid exact: 3125*128 == NF
    const u16* Cb = comb + (size_t)b * NF * 64;
    const int* nbb = nbr + ((size_t)b * NF + n) * 7;
    int i0[7];
#pragma unroll
    for (int k = 0; k < 7; k++) i0[k] = nbb[k];
    s16x8 rlo[7], rhi[7];
#pragma unroll
    for (int k = 0; k < 7; k++) {
        const u16* rec = Cb + (size_t)i0[k] * 64;
        rlo[k] = __builtin_bit_cast(s16x8, *(const u16x8*)(rec + q * 8));
        rhi[k] = __builtin_bit_cast(s16x8, *(const u16x8*)(rec + 32 + q * 8));
    }
    f4 acc0 = {0.f, 0.f, 0.f, 0.f};
    f4 acc1 = {0.f, 0.f, 0.f, 0.f};
#pragma unroll
    for (int k = 0; k < 7; k++) {
        acc0 = mfma16(wfv[(k * 4 + 0) * 64 + lane], rlo[k], acc0);
        acc1 = mfma16(wfv[(k * 4 + 1) * 64 + lane], rlo[k], acc1);
        acc0 = mfma16(wfv[(k * 4 + 2) * 64 + lane], rhi[k], acc0);
        acc1 = mfma16(wfv[(k * 4 + 3) * 64 + lane], rhi[k], acc1);
    }
    // fused stats: reduce over the 16 particles (p) per channel, f32 pre-rounding
    float s[8], t[8];
#pragma unroll
    for (int r = 0; r < 4; r++) {
        s[r] = acc0[r];     t[r] = acc0[r] * acc0[r];
        s[4 + r] = acc1[r]; t[4 + r] = acc1[r] * acc1[r];
    }
#pragma unroll
    for (int m = 1; m < 16; m <<= 1) {
#pragma unroll
        for (int j = 0; j < 8; j++) {
            s[j] += __shfl_xor(s[j], m);
            t[j] += __shfl_xor(t[j], m);
        }
    }
    if (p == 0) {
#pragma unroll
        for (int r = 0; r < 4; r++) {
            atomicAdd(&sst[(q * 4 + r) * 2],       s[r]);
            atomicAdd(&sst[(q * 4 + r) * 2 + 1],   t[r]);
            atomicAdd(&sst[(16 + q * 4 + r) * 2],     s[4 + r]);
            atomicAdd(&sst[(16 + q * 4 + r) * 2 + 1], t[4 + r]);
        }
    }
    // D: col = lane&15 = particle, row = 4*q + r = output channel
    u16x4 v0, v1;
#pragma unroll
    for (int r = 0; r < 4; r++) { v0[r] = f2b(acc0[r]); v1[r] = f2b(acc1[r]); }
    u16* out = h1 + ((size_t)b * NF + n) * CH + q * 4;
    *(u16x4*)out = v0;
    *(u16x4*)(out + 16) = v1;
    __syncthreads();
    if (tid < 64) atomicAdd(&stats1[(size_t)(b * 64 + tid) * 32], sst[tid]);
}

// ---------------- conv2: gather-GEMM, fin1+norm1+relu fused, f32 out ------------
// GN-1 finalize computed per-lane in registers (no serial wave-0 head).
__global__ __launch_bounds__(512) void k_conv2(
    const u16* __restrict__ x, const u16* __restrict__ wfg,
    const int* __restrict__ nbr, const float* __restrict__ stats1,
    const float* __restrict__ g1, const float* __restrict__ b1,
    float* __restrict__ out, float* __restrict__ stats2)
{
    __shared__ u16 wf[7 * 2 * 512];   // 14 KB shared by 8 waves
    __shared__ float sst[64];
    int tid = threadIdx.x, b = blockIdx.y;
    if (tid < 64) sst[tid] = 0.f;
    const f4* wsrc = (const f4*)wfg;
    f4* wdst = (f4*)wf;
    for (int i = tid; i < 896; i += 512) wdst[i] = wsrc[i];
    __syncthreads();
    const s16x8* wfv = (const s16x8*)wf;
    int lane = tid & 63, wave = tid >> 6;
    int p = lane & 15, q = lane >> 4;
    int n = blockIdx.x * 128 + wave * 16 + p;
    const u16* Xb = x + (size_t)b * NF * CH;
    const int* nbb = nbr + ((size_t)b * NF + n) * 7;
    int i0[7];
#pragma unroll
    for (int k = 0; k < 7; k++) i0[k] = nbb[k];
    // per-lane GN-1 finalize for this lane's 8 channels (L2-broadcast loads)
    float sc[8], sh[8];
#pragma unroll
    for (int j = 0; j < 8; j++) {
        int ch = q * 8 + j;
        float sum = stats1[(size_t)(b * 64 + ch * 2) * 32];
        float sq  = stats1[(size_t)(b * 64 + ch * 2 + 1) * 32];
        float mean = sum * (1.f / NF);
        float var = sq * (1.f / NF) - mean * mean;
        float s = rsqrtf(var + EPS) * g1[ch];
        sc[j] = s;
        sh[j] = b1[ch] - mean * s;
    }
    u16x8 raw[7];
#pragma unroll
    for (int k = 0; k < 7; k++)
        raw[k] = *(const u16x8*)(Xb + (size_t)i0[k] * CH + q * 8);
    f4 acc0 = {0.f, 0.f, 0.f, 0.f};
    f4 acc1 = {0.f, 0.f, 0.f, 0.f};
#pragma unroll
    for (int k = 0; k < 7; k++) {
        u16x8 nv;
#pragma unroll
        for (int j = 0; j < 8; j++)
            nv[j] = f2b(fmaxf(fmaf(b2f(raw[k][j]), sc[j], sh[j]), 0.f));
        s16x8 a = __builtin_bit_cast(s16x8, nv);
        acc0 = mfma16(wfv[(k * 2 + 0) * 64 + lane], a, acc0);
        acc1 = mfma16(wfv[(k * 2 + 1) * 64 + lane], a, acc1);
    }
    // fused stats2 on raw f32 conv output
    float s[8], t[8];
#pragma unroll
    for (int r = 0; r < 4; r++) {
        s[r] = acc0[r];     t[r] = acc0[r] * acc0[r];
        s[4 + r] = acc1[r]; t[4 + r] = acc1[r] * acc1[r];
    }
#pragma unroll
    for (int m = 1; m < 16; m <<= 1) {
#pragma unroll
        for (int j = 0; j < 8; j++) {
            s[j] += __shfl_xor(s[j], m);
            t[j] += __shfl_xor(t[j], m);
        }
    }
    if (p == 0) {
#pragma unroll
        for (int r = 0; r < 4; r++) {
            atomicAdd(&sst[(q * 4 + r) * 2],       s[r]);
            atomicAdd(&sst[(q * 4 + r) * 2 + 1],   t[r]);
            atomicAdd(&sst[(16 + q * 4 + r) * 2],     s[4 + r]);
            atomicAdd(&sst[(16 + q * 4 + r) * 2 + 1], t[4 + r]);
        }
    }
    // f32 transposed store: out[b][ch][n]
    float* ob = out + (size_t)b * CH * NF + n;
#pragma unroll
    for (int r = 0; r < 4; r++) {
        ob[(size_t)(q * 4 + r) * NF] = acc0[r];
        ob[(size_t)(16 + q * 4 + r) * NF] = acc1[r];
    }
    __syncthreads();
    if (tid < 64) atomicAdd(&stats2[(size_t)(b * 64 + tid) * 32], sst[tid]);
}

// ---------------- in-place fin2+normalize+relu on f32 [B][32][NF] ---------------
// Grid-stride (2048 blocks) instead of 25000 one-shot workgroups.
__global__ __launch_bounds__(256) void k_norm2c(
    float* __restrict__ h, const float* __restrict__ stats2,
    const float* __restrict__ g2, const float* __restrict__ b2)
{
    const int total = BB * CH * (NF / 4);   // 6,400,000 f4 elements
    for (int i4 = blockIdx.x * 256 + threadIdx.x; i4 < total; i4 += gridDim.x * 256) {
        int cf = i4 / (NF / 4);              // 0..63 = b*32 + c
        int o = cf & 31;
        float sum = stats2[(size_t)(cf * 2) * 32];
        float sq  = stats2[(size_t)(cf * 2 + 1) * 32];
        float mean = sum * (1.f / NF);
        float var = sq * (1.f / NF) - mean * mean;
        float sc = rsqrtf(var + EPS) * g2[o];
        float sh = b2[o] - mean * sc;
        f4 v = ((f4*)h)[i4];
#pragma unroll
        for (int j = 0; j < 4; j++) v[j] = fmaxf(fmaf(v[j], sc, sh), 0.f);
        ((f4*)h)[i4] = v;
    }
}

extern "C" void kernel_launch(void* const* d_in, const int* in_sizes, int n_in,
                              void* d_out, int out_size, void* d_ws, size_t ws_size,
                              hipStream_t stream)
{
    const float* x1 = (const float*)d_in[0];
    const float* x2 = (const float*)d_in[1];
    const float* wr = (const float*)d_in[2];
    const float* gA = (const float*)d_in[3];
    const float* bA = (const float*)d_in[4];
    const float* w1 = (const float*)d_in[5];
    const float* g1 = (const float*)d_in[6];
    const float* b1 = (const float*)d_in[7];
    const float* w2 = (const float*)d_in[8];
    const float* g2 = (const float*)d_in[9];
    const float* b2 = (const float*)d_in[10];
    const int* sidx = (const int*)d_in[11];
    const int* uidx = (const int*)d_in[12];
    const int* nbr  = (const int*)d_in[13];

    // comb [B][NF][64] bf16 = 102.4 MB lives in d_out (dead before conv2 writes
    // f32 output there). ws (~59.5 MB): h1 51.2 | y 8.19 | stats | wf tables.
    char* ws = (char*)d_ws;
    u16* h1      = (u16*)ws;                            // [B][NF][32] bf16
    u16* y       = (u16*)(ws + 51200000);               // [B][SVOX][32] bf16
    float* stats = (float*)(ws + 59392000);             // 3 x 16 KB padded accumulators
    float* statsA = stats;
    float* stats1 = (float*)(ws + 59392000 + 16384);
    float* stats2 = (float*)(ws + 59392000 + 32768);
    u16* wf1g = (u16*)(ws + 59392000 + 49152);          // 28672 B
    u16* wf2g = (u16*)(ws + 59392000 + 49152 + 28672);  // 14336 B
    u16* comb = (u16*)d_out;

    k_prep<<<1, 256, 0, stream>>>(w1, w2, stats, wf1g, wf2g);
    k_reduce<<<dim3(125, BB), 256, 0, stream>>>(x1, wr, y, statsA);
    k_build<<<dim3(1024, BB), 256, 0, stream>>>(x2, y, statsA, gA, bA, sidx, uidx, comb);
    k_conv1<<<dim3(3125, BB), 512, 0, stream>>>(comb, wf1g, nbr, h1, stats1);
    k_conv2<<<dim3(3125, BB), 512, 0, stream>>>(h1, wf2g, nbr, stats1, g1, b1, (float*)d_out, stats2);
    k_norm2c<<<2048, 256, 0, stream>>>((float*)d_out, stats2, g2, b2);
}